// Round 12
// baseline (385.808 us; speedup 1.0000x reference)
//
#include <hip/hip_runtime.h>
#include <math.h>

#define D 128
#define H 8
#define NGT 8
#define LSTOK 4   // n_global_tokens_global (fixed by problem)
#define NCH 4     // node chunks for glob_part

typedef short bf16x8 __attribute__((ext_vector_type(8)));
typedef float f32x4  __attribute__((ext_vector_type(4)));

__device__ __forceinline__ short f2bf(float f) {
  union { float f; unsigned u; } v; v.f = f;
  unsigned r = v.u + 0x7FFFu + ((v.u >> 16) & 1u);   // RNE
  return (short)(r >> 16);
}
__device__ __forceinline__ float bf2f(short s) {
  union { unsigned u; float f; } v;
  v.u = ((unsigned)(unsigned short)s) << 16;
  return v.f;
}
__device__ __forceinline__ float4 bf4(bf16x8 v, int lo) {
  return make_float4(bf2f(v[lo]), bf2f(v[lo + 1]), bf2f(v[lo + 2]), bf2f(v[lo + 3]));
}
__device__ __forceinline__ unsigned pk2(float a, float b) {
  return ((unsigned)(unsigned short)f2bf(b) << 16) | (unsigned short)f2bf(a);
}

__device__ __forceinline__ float dot4(float4 a, float4 b) {
  return a.x*b.x + a.y*b.y + a.z*b.z + a.w*b.w;
}
__device__ __forceinline__ float4 scale_madd(float4 a, float sc, float4 v, float p) {
  return make_float4(fmaf(p, v.x, a.x*sc), fmaf(p, v.y, a.y*sc),
                     fmaf(p, v.z, a.z*sc), fmaf(p, v.w, a.w*sc));
}
__device__ __forceinline__ float4 comb4(float4 a, float e1, float4 c, float e2) {
  return make_float4(a.x*e1 + c.x*e2, a.y*e1 + c.y*e2, a.z*e1 + c.z*e2, a.w*e1 + c.w*e2);
}
__device__ __forceinline__ float4 shfl_xor4(float4 v, int off) {
  return make_float4(__shfl_xor(v.x, off), __shfl_xor(v.y, off),
                     __shfl_xor(v.z, off), __shfl_xor(v.w, off));
}

// ---------------- weight fp32 -> bf16 conversion (one-shot, 10 matrices) ----------------
struct CvtArgs {
  const float* s[10];
  short*       d[10];
  int          n[10];
};

__global__ void cvt_weights(CvtArgs a) {
  int which = blockIdx.y;
  const float* s = a.s[which];
  short* d = a.d[which];
  int n = a.n[which];
  int i = (blockIdx.x * 256 + threadIdx.x) * 4;
  if (i + 3 < n) {
    float4 v = *(const float4*)(s + i);
    d[i]     = f2bf(v.x);
    d[i + 1] = f2bf(v.y);
    d[i + 2] = f2bf(v.z);
    d[i + 3] = f2bf(v.w);
  }
}

__global__ void concat_bias4(const float* __restrict__ b0, const float* __restrict__ b1,
                             const float* __restrict__ b2, const float* __restrict__ b3,
                             float* __restrict__ out) {
  int t = threadIdx.x;
  out[t] = b0[t]; out[128 + t] = b1[t]; out[256 + t] = b2[t]; out[384 + t] = b3[t];
}

// ---------------- direct MFMA GEMM (no staging LDS; small LDS for bf16 epilogue) -------
// A is bf16 (AF32=0) or fp32 (AF32=1), row-major [Nrows][K].
#define EPST 72   // LDS epilogue row stride in shorts (144B, 16B-aligned)
template<int K, int AF32>
__global__ void __launch_bounds__(256) gemm_direct(const void* __restrict__ A,
    const short* __restrict__ Wb, const float* __restrict__ bias,
    short* __restrict__ out16, int C16, int s16,
    float* __restrict__ out32, int s32,
    int Nrows, int Ccols, int relu)
{
  __shared__ short eplds[4][32 * EPST];
  const int t = threadIdx.x;
  const int wid = t >> 6, lane = t & 63;
  const int rowBase = blockIdx.x * 128 + (wid >> 1) * 64;
  const int colBase = blockIdx.y * 128 + (wid & 1) * 64;
  const int lrow = lane & 15;
  const int lk = (lane >> 4) * 8;

  f32x4 acc[4][4];
  f32x4 z4 = {0.f, 0.f, 0.f, 0.f};
#pragma unroll
  for (int m = 0; m < 4; m++)
#pragma unroll
    for (int n = 0; n < 4; n++) acc[m][n] = z4;

  size_t aidx[4];
#pragma unroll
  for (int m = 0; m < 4; ++m) {
    int ar = rowBase + m * 16 + lrow;
    if (ar >= Nrows) ar = Nrows - 1;
    aidx[m] = (size_t)ar * K + lk;
  }
  const short* wp[4];
#pragma unroll
  for (int n = 0; n < 4; ++n)
    wp[n] = Wb + (size_t)(colBase + n * 16 + lrow) * K + lk;

  const short* A16 = (const short*)A;
  const float* A32 = (const float*)A;

#pragma unroll
  for (int kb = 0; kb < K; kb += 32) {
    bf16x8 af[4], bfr[4];
#pragma unroll
    for (int m = 0; m < 4; ++m) {
      if (AF32) {
        float4 f0 = *(const float4*)(A32 + aidx[m] + kb);
        float4 f1 = *(const float4*)(A32 + aidx[m] + kb + 4);
        bf16x8 v;
        v[0] = f2bf(f0.x); v[1] = f2bf(f0.y); v[2] = f2bf(f0.z); v[3] = f2bf(f0.w);
        v[4] = f2bf(f1.x); v[5] = f2bf(f1.y); v[6] = f2bf(f1.z); v[7] = f2bf(f1.w);
        af[m] = v;
      } else {
        af[m] = *(const bf16x8*)(A16 + aidx[m] + kb);
      }
    }
#pragma unroll
    for (int n = 0; n < 4; ++n) bfr[n] = *(const bf16x8*)(wp[n] + kb);
#pragma unroll
    for (int m = 0; m < 4; ++m)
#pragma unroll
      for (int n = 0; n < 4; ++n)
        acc[m][n] = __builtin_amdgcn_mfma_f32_16x16x32_bf16(af[m], bfr[n], acc[m][n], 0, 0, 0);
  }

  const int ccol = lane & 15;
  const int rquad = (lane >> 4) * 4;
  if (colBase < C16) {
    // bf16 output: two 32-row passes through wave-private LDS -> full-line stores
    short* lds = eplds[wid];
    float bb[4];
#pragma unroll
    for (int n = 0; n < 4; ++n) bb[n] = bias[colBase + n * 16 + ccol];
#pragma unroll
    for (int half = 0; half < 2; ++half) {
#pragma unroll
      for (int n = 0; n < 4; ++n) {
        int col = n * 16 + ccol;
#pragma unroll
        for (int mm = 0; mm < 2; ++mm) {
          int m = half * 2 + mm;
          int r0 = mm * 16 + rquad;
#pragma unroll
          for (int r = 0; r < 4; ++r) {
            float v = acc[m][n][r] + bb[n];
            if (relu) v = fmaxf(v, 0.f);
            lds[(r0 + r) * EPST + col] = f2bf(v);
          }
        }
      }
      const int jr = lane >> 3, jc = lane & 7;
#pragma unroll
      for (int i = 0; i < 4; ++i) {
        int row = i * 8 + jr;
        int gr = rowBase + half * 32 + row;
        if (gr < Nrows) {
          bf16x8 v = *(const bf16x8*)(lds + row * EPST + jc * 8);
          *(bf16x8*)(out16 + (size_t)gr * s16 + colBase + jc * 8) = v;
        }
      }
    }
  } else {
#pragma unroll
    for (int n = 0; n < 4; ++n) {
      int col = colBase + n * 16 + ccol;
      float bb = bias[col];
#pragma unroll
      for (int m = 0; m < 4; ++m) {
        int row0 = rowBase + m * 16 + rquad;
#pragma unroll
        for (int r = 0; r < 4; ++r) {
          int gr = row0 + r;
          if (gr < Nrows) {
            float v = acc[m][n][r] + bb;
            if (relu) v = fmaxf(v, 0.f);
            out32[(size_t)gr * s32 + (col - C16)] = v;
          }
        }
      }
    }
  }
}

// ---------------- fused FF (64-row tiles): out = relu(A@W1^T+b1)@W2^T+b2 ----------------
#define FFST 264   // LDS row stride in shorts for the 256-wide ff1 tile
__global__ void __launch_bounds__(256) gemm_ff(const short* __restrict__ A,
    const short* __restrict__ W1b, const float* __restrict__ b1,
    const short* __restrict__ W2b, const float* __restrict__ b2,
    float* __restrict__ out, int Nrows)
{
  __shared__ short flds[64 * FFST];
  const int t = threadIdx.x;
  const int wid = t >> 6, lane = t & 63;
  const int rowBase = blockIdx.x * 64;
  const int lrow = lane & 15;
  const int lk = (lane >> 4) * 8;
  const int ccol = lane & 15;
  const int rquad = (lane >> 4) * 4;
  f32x4 z4 = {0.f, 0.f, 0.f, 0.f};

  size_t aidx[4];
#pragma unroll
  for (int m = 0; m < 4; ++m) {
    int ar = rowBase + m * 16 + lrow;
    if (ar >= Nrows) ar = Nrows - 1;
    aidx[m] = (size_t)ar * 128 + lk;
  }

  // ---- stage A: ff1 tile (64 x 256); wave w owns cols w*64..w*64+64 ----
  {
    int colBase = wid * 64;
    f32x4 acc[4][4];
#pragma unroll
    for (int m = 0; m < 4; m++)
#pragma unroll
      for (int n = 0; n < 4; n++) acc[m][n] = z4;
    const short* wp[4];
#pragma unroll
    for (int n = 0; n < 4; ++n)
      wp[n] = W1b + (size_t)(colBase + n * 16 + lrow) * 128 + lk;
#pragma unroll
    for (int kb = 0; kb < 128; kb += 32) {
      bf16x8 af[4], bfr[4];
#pragma unroll
      for (int m = 0; m < 4; ++m) af[m] = *(const bf16x8*)(A + aidx[m] + kb);
#pragma unroll
      for (int n = 0; n < 4; ++n) bfr[n] = *(const bf16x8*)(wp[n] + kb);
#pragma unroll
      for (int m = 0; m < 4; ++m)
#pragma unroll
        for (int n = 0; n < 4; ++n)
          acc[m][n] = __builtin_amdgcn_mfma_f32_16x16x32_bf16(af[m], bfr[n], acc[m][n], 0, 0, 0);
    }
#pragma unroll
    for (int n = 0; n < 4; ++n) {
      int col = colBase + n * 16 + ccol;
      float bb = b1[col];
#pragma unroll
      for (int m = 0; m < 4; ++m) {
        int r0 = m * 16 + rquad;
#pragma unroll
        for (int r = 0; r < 4; ++r) {
          float v = fmaxf(acc[m][n][r] + bb, 0.f);
          flds[(r0 + r) * FFST + col] = f2bf(v);
        }
      }
    }
  }
  __syncthreads();

  // ---- stage B: out(64x128) = ff1 @ W2^T + b2, K=256; wave w: rows 32*(w>>1), cols 64*(w&1) ----
  {
    int rowL = (wid >> 1) * 32;
    int colBase = (wid & 1) * 64;
    f32x4 acc[2][4];
#pragma unroll
    for (int m = 0; m < 2; m++)
#pragma unroll
      for (int n = 0; n < 4; n++) acc[m][n] = z4;
    const short* wp[4];
#pragma unroll
    for (int n = 0; n < 4; ++n)
      wp[n] = W2b + (size_t)(colBase + n * 16 + lrow) * 256 + lk;
#pragma unroll
    for (int kb = 0; kb < 256; kb += 32) {
      bf16x8 af[2], bfr[4];
#pragma unroll
      for (int m = 0; m < 2; ++m)
        af[m] = *(const bf16x8*)(flds + (rowL + m * 16 + lrow) * FFST + kb + lk);
#pragma unroll
      for (int n = 0; n < 4; ++n) bfr[n] = *(const bf16x8*)(wp[n] + kb);
#pragma unroll
      for (int m = 0; m < 2; ++m)
#pragma unroll
        for (int n = 0; n < 4; ++n)
          acc[m][n] = __builtin_amdgcn_mfma_f32_16x16x32_bf16(af[m], bfr[n], acc[m][n], 0, 0, 0);
    }
#pragma unroll
    for (int n = 0; n < 4; ++n) {
      int col = colBase + n * 16 + ccol;
      float bb = b2[col];
#pragma unroll
      for (int m = 0; m < 2; ++m) {
        int row0 = rowBase + rowL + m * 16 + rquad;
#pragma unroll
        for (int r = 0; r < 4; ++r) {
          int gr = row0 + r;
          if (gr < Nrows) out[(size_t)gr * 128 + col] = acc[m][n][r] + bb;
        }
      }
    }
  }
}

// small GEMM (M rows <= 64, K=C=128): one block per row
__global__ void gemm_small(const float* __restrict__ A, const float* __restrict__ W,
                           const float* __restrict__ bias, float* __restrict__ out, int M)
{
  int r = blockIdx.x;
  int c = threadIdx.x;
  __shared__ float as[128];
  as[c] = A[(size_t)r * 128 + c];
  __syncthreads();
  float acc = bias[c];
  const float* wr = W + (size_t)c * 128;
#pragma unroll 4
  for (int k = 0; k < 128; k++) acc += as[k] * wr[k];
  out[(size_t)r * 128 + c] = acc;
}

// ---------------- CSR build ----------------
__global__ void count_deg(const int* __restrict__ dst, int* __restrict__ deg, int E) {
  int e = blockIdx.x * 256 + threadIdx.x;
  if (e < E) atomicAdd(&deg[dst[e]], 1);
}

__global__ void scan_pass1(const int* __restrict__ deg, int* __restrict__ bsum, int N) {
  int t = threadIdx.x, lane = t & 63, wid = t >> 6;
  int idx = blockIdx.x * 1024 + t * 4;
  int4 v = {0, 0, 0, 0};
  if (idx + 3 < N) v = *(const int4*)(deg + idx);
  else {
    if (idx < N) v.x = deg[idx];
    if (idx + 1 < N) v.y = deg[idx + 1];
    if (idx + 2 < N) v.z = deg[idx + 2];
    if (idx + 3 < N) v.w = deg[idx + 3];
  }
  int s = v.x + v.y + v.z + v.w;
#pragma unroll
  for (int off = 32; off >= 1; off >>= 1) s += __shfl_xor(s, off);
  __shared__ int ws[4];
  if (lane == 0) ws[wid] = s;
  __syncthreads();
  if (t == 0) bsum[blockIdx.x] = ws[0] + ws[1] + ws[2] + ws[3];
}

__global__ void scan_pass2(int* __restrict__ bsum, int SB) {
  __shared__ int sh[1024];
  int t = threadIdx.x;
  sh[t] = (t < SB) ? bsum[t] : 0;
  __syncthreads();
  for (int off = 1; off < 1024; off <<= 1) {
    int v = (t >= off) ? sh[t - off] : 0;
    __syncthreads();
    sh[t] += v;
    __syncthreads();
  }
  if (t < SB) bsum[t] = (t == 0) ? 0 : sh[t - 1];
}

__global__ void scan_pass3(const int* __restrict__ deg, const int* __restrict__ bsum,
                           int* __restrict__ row_start, int* __restrict__ cursor,
                           int N, int E)
{
  int t = threadIdx.x, lane = t & 63, wid = t >> 6;
  int idx = blockIdx.x * 1024 + t * 4;
  int4 v = {0, 0, 0, 0};
  if (idx + 3 < N) v = *(const int4*)(deg + idx);
  else {
    if (idx < N) v.x = deg[idx];
    if (idx + 1 < N) v.y = deg[idx + 1];
    if (idx + 2 < N) v.z = deg[idx + 2];
    if (idx + 3 < N) v.w = deg[idx + 3];
  }
  int ts = v.x + v.y + v.z + v.w;
  int x = ts;
#pragma unroll
  for (int off = 1; off < 64; off <<= 1) {
    int y = __shfl_up(x, off);
    if (lane >= off) x += y;
  }
  __shared__ int ws[4];
  if (lane == 63) ws[wid] = x;
  __syncthreads();
  int woff = 0;
  for (int i = 0; i < wid; i++) woff += ws[i];
  int p = bsum[blockIdx.x] + woff + (x - ts);
  if (idx < N)     { row_start[idx] = p; cursor[idx] = p; }     p += v.x;
  if (idx + 1 < N) { row_start[idx + 1] = p; cursor[idx + 1] = p; } p += v.y;
  if (idx + 2 < N) { row_start[idx + 2] = p; cursor[idx + 2] = p; } p += v.z;
  if (idx + 3 < N) { row_start[idx + 3] = p; cursor[idx + 3] = p; }
  if (blockIdx.x == 0 && t == 0) row_start[N] = E;
}

__global__ void fill_edges(const int* __restrict__ dst, const int* __restrict__ src,
                           int* __restrict__ cursor, int* __restrict__ edge_src, int E) {
  int e = blockIdx.x * 256 + threadIdx.x;
  if (e < E) {
    int p = atomicAdd(&cursor[dst[e]], 1);
    edge_src[p] = src[e];
  }
}

// ---------------- tconv edge attention: q|k|v|xr bf16 (qkvb stride 512) ----------------
__global__ void tconv_attn(const short* __restrict__ qkvb,
                           const int* __restrict__ row_start,
                           const int* __restrict__ edge_src,
                           float* __restrict__ out, int N)
{
  int gid = blockIdx.x * 256 + threadIdx.x;
  if (gid >= N * H) return;
  int n = gid >> 3, h = gid & 7;
  const short* qp = qkvb + (size_t)n * 512 + h * 16;
  bf16x8 qa = *(const bf16x8*)(qp);
  bf16x8 qb = *(const bf16x8*)(qp + 8);
  float4 q0 = bf4(qa, 0), q1 = bf4(qa, 4), q2 = bf4(qb, 0), q3 = bf4(qb, 4);
  int e0 = row_start[n], e1 = row_start[n + 1];

  float mA = -3.0e38f, sA = 0.f;
  float4 A0 = make_float4(0, 0, 0, 0), A1 = A0, A2 = A0, A3 = A0;
  float mB = -3.0e38f, sB = 0.f;
  float4 B0 = A0, B1 = A0, B2 = A0, B3 = A0;

  int ei = e0;
  for (; ei + 1 < e1; ei += 2) {
    int sn0 = edge_src[ei], sn1 = edge_src[ei + 1];
    const short* kp0 = qkvb + (size_t)sn0 * 512 + 128 + h * 16;
    const short* kp1 = qkvb + (size_t)sn1 * 512 + 128 + h * 16;
    bf16x8 k00 = *(const bf16x8*)(kp0);
    bf16x8 k01 = *(const bf16x8*)(kp0 + 8);
    bf16x8 k10 = *(const bf16x8*)(kp1);
    bf16x8 k11 = *(const bf16x8*)(kp1 + 8);
    float d0 = (dot4(q0, bf4(k00, 0)) + dot4(q1, bf4(k00, 4))
              + dot4(q2, bf4(k01, 0)) + dot4(q3, bf4(k01, 4))) * 0.25f;
    float d1 = (dot4(q0, bf4(k10, 0)) + dot4(q1, bf4(k10, 4))
              + dot4(q2, bf4(k11, 0)) + dot4(q3, bf4(k11, 4))) * 0.25f;
    bf16x8 v00 = *(const bf16x8*)(kp0 + 128);
    bf16x8 v01 = *(const bf16x8*)(kp0 + 136);
    bf16x8 v10 = *(const bf16x8*)(kp1 + 128);
    bf16x8 v11 = *(const bf16x8*)(kp1 + 136);
    float mn0 = fmaxf(mA, d0);
    float sc0 = expf(mA - mn0), p0 = expf(d0 - mn0);
    A0 = scale_madd(A0, sc0, bf4(v00, 0), p0);
    A1 = scale_madd(A1, sc0, bf4(v00, 4), p0);
    A2 = scale_madd(A2, sc0, bf4(v01, 0), p0);
    A3 = scale_madd(A3, sc0, bf4(v01, 4), p0);
    sA = sA * sc0 + p0; mA = mn0;
    float mn1 = fmaxf(mB, d1);
    float sc1 = expf(mB - mn1), p1 = expf(d1 - mn1);
    B0 = scale_madd(B0, sc1, bf4(v10, 0), p1);
    B1 = scale_madd(B1, sc1, bf4(v10, 4), p1);
    B2 = scale_madd(B2, sc1, bf4(v11, 0), p1);
    B3 = scale_madd(B3, sc1, bf4(v11, 4), p1);
    sB = sB * sc1 + p1; mB = mn1;
  }
  if (ei < e1) {
    int sn0 = edge_src[ei];
    const short* kp0 = qkvb + (size_t)sn0 * 512 + 128 + h * 16;
    bf16x8 k00 = *(const bf16x8*)(kp0);
    bf16x8 k01 = *(const bf16x8*)(kp0 + 8);
    float d0 = (dot4(q0, bf4(k00, 0)) + dot4(q1, bf4(k00, 4))
              + dot4(q2, bf4(k01, 0)) + dot4(q3, bf4(k01, 4))) * 0.25f;
    bf16x8 v00 = *(const bf16x8*)(kp0 + 128);
    bf16x8 v01 = *(const bf16x8*)(kp0 + 136);
    float mn0 = fmaxf(mA, d0);
    float sc0 = expf(mA - mn0), p0 = expf(d0 - mn0);
    A0 = scale_madd(A0, sc0, bf4(v00, 0), p0);
    A1 = scale_madd(A1, sc0, bf4(v00, 4), p0);
    A2 = scale_madd(A2, sc0, bf4(v01, 0), p0);
    A3 = scale_madd(A3, sc0, bf4(v01, 4), p0);
    sA = sA * sc0 + p0; mA = mn0;
  }
  float mn = fmaxf(mA, mB);
  float eA = expf(mA - mn), eB = expf(mB - mn);
  float s = sA * eA + sB * eB;
  float4 a0 = comb4(A0, eA, B0, eB);
  float4 a1 = comb4(A1, eA, B1, eB);
  float4 a2 = comb4(A2, eA, B2, eB);
  float4 a3 = comb4(A3, eA, B3, eB);
  float inv = 1.f / (s + 1e-16f);
  float4* o4 = (float4*)(out + (size_t)n * 128 + h * 16);
  o4[0] = make_float4(a0.x * inv, a0.y * inv, a0.z * inv, a0.w * inv);
  o4[1] = make_float4(a1.x * inv, a1.y * inv, a1.z * inv, a1.w * inv);
  o4[2] = make_float4(a2.x * inv, a2.y * inv, a2.z * inv, a2.w * inv);
  o4[3] = make_float4(a3.x * inv, a3.y * inv, a3.z * inv, a3.w * inv);
}

// ---------------- gate + residual + LN -> x1 (fp32) + x1b (bf16); xr bf16 in qkvb ------
__global__ void gate_ln(const float* __restrict__ x, const float* __restrict__ att,
                        const short* __restrict__ qkvb, const float* __restrict__ Wb,
                        float* __restrict__ x1, short* __restrict__ x1b, int N)
{
  int wid = threadIdx.x >> 6, lane = threadIdx.x & 63;
  int n = blockIdx.x * 4 + wid;
  if (n >= N) return;
  size_t base = (size_t)n * 128 + lane * 2;
  float2 o = *(const float2*)(att + base);
  unsigned ru = *(const unsigned*)(qkvb + (size_t)n * 512 + 384 + lane * 2);
  float2 r = make_float2(bf2f((short)(ru & 0xFFFF)), bf2f((short)(ru >> 16)));
  float2 xv = *(const float2*)(x + base);
  float2 w0 = *(const float2*)(Wb + lane * 2);
  float2 w1 = *(const float2*)(Wb + 128 + lane * 2);
  float2 w2 = *(const float2*)(Wb + 256 + lane * 2);
  float ts = o.x * w0.x + o.y * w0.y + r.x * w1.x + r.y * w1.y
           + (o.x - r.x) * w2.x + (o.y - r.y) * w2.y;
#pragma unroll
  for (int mm = 32; mm >= 1; mm >>= 1) ts += __shfl_xor(ts, mm);
  float beta = 1.f / (1.f + expf(-ts));
  float2 y;
  y.x = xv.x + beta * r.x + (1.f - beta) * o.x;
  y.y = xv.y + beta * r.y + (1.f - beta) * o.y;
  float sm = y.x + y.y;
#pragma unroll
  for (int mm = 32; mm >= 1; mm >>= 1) sm += __shfl_xor(sm, mm);
  float mean = sm * (1.f / 128.f);
  float dx = y.x - mean, dy = y.y - mean;
  float vs = dx * dx + dy * dy;
#pragma unroll
  for (int mm = 32; mm >= 1; mm >>= 1) vs += __shfl_xor(vs, mm);
  float rstd = rsqrtf(vs * (1.f / 128.f) + 1e-5f);
  float ox = dx * rstd, oy = dy * rstd;
  *(float2*)(x1 + base) = make_float2(ox, oy);
  *(unsigned*)(x1b + base) = pk2(ox, oy);
}

// ---------------- out = LN(a + b); optional bf16 copy ----------------
__global__ void ln_add(const float* __restrict__ a, const float* __restrict__ b,
                       float* __restrict__ out, short* __restrict__ out16, int R)
{
  int wid = threadIdx.x >> 6, lane = threadIdx.x & 63;
  int r = blockIdx.x * 4 + wid;
  if (r >= R) return;
  size_t base = (size_t)r * 128 + lane * 2;
  float2 av = *(const float2*)(a + base);
  float2 bv = *(const float2*)(b + base);
  float2 y = make_float2(av.x + bv.x, av.y + bv.y);
  float sm = y.x + y.y;
#pragma unroll
  for (int mm = 32; mm >= 1; mm >>= 1) sm += __shfl_xor(sm, mm);
  float mean = sm * (1.f / 128.f);
  float dx = y.x - mean, dy = y.y - mean;
  float vs = dx * dx + dy * dy;
#pragma unroll
  for (int mm = 32; mm >= 1; mm >>= 1) vs += __shfl_xor(vs, mm);
  float rstd = rsqrtf(vs * (1.f / 128.f) + 1e-5f);
  float ox = dx * rstd, oy = dy * rstd;
  *(float2*)(out + base) = make_float2(ox, oy);
  if (out16) *(unsigned*)(out16 + base) = pk2(ox, oy);
}

// ---------------- glob attention, pass 1: partial online softmax over node chunks ------
__global__ void glob_part(const float* __restrict__ Qg, const short* __restrict__ kv,
                          short* __restrict__ Plog,
                          float* __restrict__ pm, float* __restrict__ ps,
                          float* __restrict__ pacc, int MAXN)
{
  int blk = blockIdx.x;                 // b*64 + g*8 + h
  int ch = blockIdx.y;
  int h = blk & 7, g = (blk >> 3) & 7, b = blk >> 6;
  int lane = threadIdx.x;
  const float4* q4 = (const float4*)(Qg + (size_t)(b * NGT + g) * 128 + h * 16);
  float4 q0 = q4[0], q1 = q4[1], q2 = q4[2], q3 = q4[3];
  int chunk = (MAXN + NCH - 1) / NCH;
  int n0 = ch * chunk;
  int n1 = n0 + chunk; if (n1 > MAXN) n1 = MAXN;
  short* plrow = (g >= LSTOK) ? Plog + (((size_t)(b * 4 + g - LSTOK)) * H + h) * MAXN : nullptr;
  float m = -3.0e38f, s = 0.f;
  float4 a0 = make_float4(0, 0, 0, 0), a1 = a0, a2 = a0, a3 = a0;
  for (int n = n0 + lane; n < n1; n += 64) {
    const short* kp = kv + ((size_t)(b * MAXN + n)) * 256 + h * 16;
    bf16x8 k0 = *(const bf16x8*)(kp);
    bf16x8 k1 = *(const bf16x8*)(kp + 8);
    float d = dot4(q0, bf4(k0, 0)) + dot4(q1, bf4(k0, 4))
            + dot4(q2, bf4(k1, 0)) + dot4(q3, bf4(k1, 4));
    d *= 0.25f;
    if (plrow) plrow[n] = f2bf(d);
    float mn = fmaxf(m, d);
    float sc = expf(m - mn);
    float p = expf(d - mn);
    bf16x8 v0 = *(const bf16x8*)(kp + 128);
    bf16x8 v1 = *(const bf16x8*)(kp + 136);
    a0 = scale_madd(a0, sc, bf4(v0, 0), p);
    a1 = scale_madd(a1, sc, bf4(v0, 4), p);
    a2 = scale_madd(a2, sc, bf4(v1, 0), p);
    a3 = scale_madd(a3, sc, bf4(v1, 4), p);
    s = s * sc + p;
    m = mn;
  }
#pragma unroll
  for (int off = 32; off >= 1; off >>= 1) {
    float m2 = __shfl_xor(m, off);
    float s2 = __shfl_xor(s, off);
    float4 c0 = shfl_xor4(a0, off), c1 = shfl_xor4(a1, off);
    float4 c2 = shfl_xor4(a2, off), c3 = shfl_xor4(a3, off);
    float mn = fmaxf(m, m2);
    float e1 = expf(m - mn), e2 = expf(m2 - mn);
    s = s * e1 + s2 * e2;
    a0 = comb4(a0, e1, c0, e2);
    a1 = comb4(a1, e1, c1, e2);
    a2 = comb4(a2, e1, c2, e2);
    a3 = comb4(a3, e1, c3, e2);
    m = mn;
  }
  if (lane == 0) {
    int pi = blk * NCH + ch;
    pm[pi] = m; ps[pi] = s;
    float4* pa = (float4*)(pacc + (size_t)pi * 16);
    pa[0] = a0; pa[1] = a1; pa[2] = a2; pa[3] = a3;
  }
}

__global__ void glob_merge(const float* __restrict__ pm, const float* __restrict__ ps,
                           const float* __restrict__ pacc, float* __restrict__ Og,
                           float* __restrict__ m_gl, float* __restrict__ is_gl)
{
  int blk = blockIdx.x;
  int lane = threadIdx.x;
  float m = -3.0e38f;
#pragma unroll
  for (int c = 0; c < NCH; ++c) m = fmaxf(m, pm[blk * NCH + c]);
  float s = 0.f;
#pragma unroll
  for (int c = 0; c < NCH; ++c) s += ps[blk * NCH + c] * expf(pm[blk * NCH + c] - m);
  if (lane < 16) {
    float a = 0.f;
#pragma unroll
    for (int c = 0; c < NCH; ++c)
      a += pacc[(size_t)(blk * NCH + c) * 16 + lane] * expf(pm[blk * NCH + c] - m);
    int h = blk & 7, g = (blk >> 3) & 7, b = blk >> 6;
    Og[(size_t)(b * NGT + g) * 128 + h * 16 + lane] = a / s;
  }
  if (lane == 0) { m_gl[blk] = m; is_gl[blk] = 1.f / s; }
}

// ---------------- P rows from stored logits (bf16) ----------------
__global__ void pker2(const short* __restrict__ Plog,
                      const float* __restrict__ m_gl, const float* __restrict__ is_gl,
                      float* __restrict__ P, int MAXN)
{
  int b = blockIdx.y;
  __shared__ float ms[32], iss[32];
  if (threadIdx.x < 32) {
    int g = threadIdx.x >> 3, h = threadIdx.x & 7;
    ms[threadIdx.x]  = m_gl[(b * NGT + LSTOK + g) * H + h];
    iss[threadIdx.x] = is_gl[(b * NGT + LSTOK + g) * H + h];
  }
  __syncthreads();
  int n = blockIdx.x * 256 + threadIdx.x;
  if (n >= MAXN) return;
#pragma unroll
  for (int g = 0; g < 4; g++) {
    float acc = 0.f;
#pragma unroll
    for (int h = 0; h < H; h++) {
      float l = bf2f(Plog[(((size_t)(b * 4 + g)) * H + h) * MAXN + n]);
      acc += expf(l - ms[g * 8 + h]) * iss[g * 8 + h];
    }
    P[(size_t)(b * 4 + g) * MAXN + n] = acc * 0.125f;
  }
}

// ---------------- reg: off-diagonal Gram of row-normalized P ----------------
__global__ void regk(const float* __restrict__ P, float* __restrict__ offb, int MAXN)
{
  int b = blockIdx.x;
  int t = threadIdx.x;
  float v[10];
#pragma unroll
  for (int i = 0; i < 10; i++) v[i] = 0.f;
  for (int n = t; n < MAXN; n += 256) {
    float p0 = P[(size_t)(b * 4 + 0) * MAXN + n];
    float p1 = P[(size_t)(b * 4 + 1) * MAXN + n];
    float p2 = P[(size_t)(b * 4 + 2) * MAXN + n];
    float p3 = P[(size_t)(b * 4 + 3) * MAXN + n];
    v[0] += p0; v[1] += p1; v[2] += p2; v[3] += p3;
    v[4] += p0 * p1; v[5] += p0 * p2; v[6] += p0 * p3;
    v[7] += p1 * p2; v[8] += p1 * p3; v[9] += p2 * p3;
  }
#pragma unroll
  for (int i = 0; i < 10; i++) {
    float x = v[i];
#pragma unroll
    for (int mm = 32; mm >= 1; mm >>= 1) x += __shfl_xor(x, mm);
    v[i] = x;
  }
  __shared__ float red[4][10];
  int wid = t >> 6, lane = t & 63;
  if (lane == 0)
    for (int i = 0; i < 10; i++) red[wid][i] = v[i];
  __syncthreads();
  if (t == 0) {
    float r[10];
    for (int i = 0; i < 10; i++) r[i] = red[0][i] + red[1][i] + red[2][i] + red[3][i];
    float r0 = r[0] + 1e-8f, r1 = r[1] + 1e-8f, r2 = r[2] + 1e-8f, r3 = r[3] + 1e-8f;
    float off = 2.f * (r[4] / (r0 * r1) + r[5] / (r0 * r2) + r[6] / (r0 * r3)
                     + r[7] / (r1 * r2) + r[8] / (r1 * r3) + r[9] / (r2 * r3));
    offb[b] = off * (1.f / 12.f);   // (Kt*Kt - Kt) = 12
  }
}

__global__ void regfin(const float* __restrict__ offb, float* __restrict__ out) {
  if (threadIdx.x == 0 && blockIdx.x == 0) {
    float s = 0.f;
    for (int i = 0; i < 8; i++) s += offb[i];
    *out = s * (1.f / 8.f);
  }
}

// ---------------- nodes attend to 8 global tokens; Qn bf16 in, On bf16 out ----------------
__global__ void node_attn(const short* __restrict__ Qn, const float* __restrict__ Kg,
                          const float* __restrict__ Vg, short* __restrict__ On,
                          int N, int MAXN)
{
  __shared__ float kg[2][NGT * 128];
  __shared__ float vg[2][NGT * 128];
  int n0 = blockIdx.x * 32;
  int b0 = n0 / MAXN;
  int nlast = n0 + 31; if (nlast >= N) nlast = N - 1;
  int bLast = nlast / MAXN;
  int nb = (bLast != b0) ? 2 : 1;
  for (int bi = 0; bi < nb; ++bi) {
    size_t gb = (size_t)((b0 + bi) * NGT) * 128;
    int i = threadIdx.x * 4;
    *(float4*)&kg[bi][i] = *(const float4*)(Kg + gb + i);
    *(float4*)&vg[bi][i] = *(const float4*)(Vg + gb + i);
  }
  __syncthreads();
  int n = n0 + (threadIdx.x >> 3), h = threadIdx.x & 7;
  if (n >= N) return;
  int bi = (n / MAXN) - b0;
  const short* qp = Qn + (size_t)n * 128 + h * 16;
  bf16x8 qa = *(const bf16x8*)(qp);
  bf16x8 qb = *(const bf16x8*)(qp + 8);
  float4 q0 = bf4(qa, 0), q1 = bf4(qa, 4), q2 = bf4(qb, 0), q3 = bf4(qb, 4);
  float l[NGT];
  float mx = -3.0e38f;
#pragma unroll
  for (int tk = 0; tk < NGT; tk++) {
    const float4* k4 = (const float4*)(&kg[bi][tk * 128 + h * 16]);
    float d = dot4(q0, k4[0]) + dot4(q1, k4[1]) + dot4(q2, k4[2]) + dot4(q3, k4[3]);
    l[tk] = d * 0.25f;
    mx = fmaxf(mx, l[tk]);
  }
  float s = 0.f;
#pragma unroll
  for (int tk = 0; tk < NGT; tk++) { l[tk] = expf(l[tk] - mx); s += l[tk]; }
  float inv = 1.f / s;
  float4 a0 = make_float4(0, 0, 0, 0), a1 = a0, a2 = a0, a3 = a0;
#pragma unroll
  for (int tk = 0; tk < NGT; tk++) {
    float p = l[tk] * inv;
    const float4* v4 = (const float4*)(&vg[bi][tk * 128 + h * 16]);
    a0 = scale_madd(a0, 1.f, v4[0], p);
    a1 = scale_madd(a1, 1.f, v4[1], p);
    a2 = scale_madd(a2, 1.f, v4[2], p);
    a3 = scale_madd(a3, 1.f, v4[3], p);
  }
  unsigned* o = (unsigned*)(On + (size_t)n * 128 + h * 16);
  o[0] = pk2(a0.x, a0.y); o[1] = pk2(a0.z, a0.w);
  o[2] = pk2(a1.x, a1.y); o[3] = pk2(a1.z, a1.w);
  o[4] = pk2(a2.x, a2.y); o[5] = pk2(a2.z, a2.w);
  o[6] = pk2(a3.x, a3.y); o[7] = pk2(a3.z, a3.w);
}

extern "C" void kernel_launch(void* const* d_in, const int* in_sizes, int n_in,
                              void* d_out, int out_size, void* d_ws, size_t ws_size,
                              hipStream_t stream)
{
  const float* x     = (const float*)d_in[0];
  const int*   ei    = (const int*)d_in[1];
  const float* gh    = (const float*)d_in[2];
  const float* Wq    = (const float*)d_in[6];
  const float* bqv   = (const float*)d_in[7];
  const float* Wk    = (const float*)d_in[8];
  const float* bkv   = (const float*)d_in[9];
  const float* Wv    = (const float*)d_in[10];
  const float* bvv   = (const float*)d_in[11];
  const float* Wsk   = (const float*)d_in[12];
  const float* bsk   = (const float*)d_in[13];
  const float* Wbeta = (const float*)d_in[14];
  const float* ngw   = (const float*)d_in[15];
  const float* ngb   = (const float*)d_in[16];
  const float* ngow  = (const float*)d_in[17];
  const float* ngob  = (const float*)d_in[18];
  const float* gnw   = (const float*)d_in[19];
  const float* gnb   = (const float*)d_in[20];
  const float* gnow  = (const float*)d_in[21];
  const float* gnob  = (const float*)d_in[22];
  const float* W1    = (const float*)d_in[23];
  const float* b1v   = (const float*)d_in[24];
  const float* W2    = (const float*)d_in[25];
  const float* b2v   = (const float*)d_in[26];

  const int N    = in_sizes[0] / D;   // 50000
  const int E    = in_sizes[1] / 2;   // 400000
  const int Bb   = 8;
  const int MAXN = N / Bb;            // 6250

  const int* srcI = ei;
  const int* dstI = ei + E;

  size_t NF = (size_t)N;
  size_t ND = NF * D;
  float* fw = (float*)d_ws;
  short* qkvb = (short*)fw;              // N x 512 bf16 (q|k|v|xr)
  short* kv16 = qkvb;                    // N x 256 bf16 (aliases; qkvb dead by then)
  short* Qnb  = qkvb + NF * 256;         // N x 128 bf16 (after kv16 dead)
  short* Onb  = qkvb + NF * 384;         // N x 128 bf16
  float* ff2o = fw + NF * 256;           // N x 128 f32
  float* x1   = fw + NF * 384;           // N x 128 f32
  short* x1b  = (short*)(fw + NF * 512); // N x 128 bf16
  float* misc = fw + NF * 576;
  float* Qg    = misc;                // 64*128
  float* Og    = Qg + 8192;
  float* gout  = Og + 8192;
  float* Kg    = gout + 8192;
  float* Vg    = Kg + 8192;
  float* m_gl  = Vg + 8192;           // 512
  float* is_gl = m_gl + 512;          // 512
  float* Pbuf  = is_gl + 512;         // 8*4*MAXN
  float* offb  = Pbuf + (size_t)Bb * 4 * MAXN;   // 8 (+pad)
  float* bias512 = offb + 16;         // 512
  short* Plog  = (short*)(bias512 + 512);       // 4*8*8*MAXN bf16
  float* pm    = (float*)(Plog + (size_t)4 * H * Bb * MAXN) + 64;  // aligned-ish
  float* ps    = pm + 512 * NCH;
  float* pacc  = ps + 512 * NCH;      // 512*NCH*16
  int* deg       = (int*)(pacc + 512 * NCH * 16);
  int* row_start = deg + N;           // N+1
  int* cursor    = row_start + N + 1;
  int* bsum      = cursor + N;        // <=1024
  int* edge_src  = bsum + 1024;       // E
  short* wbase = (short*)((((uintptr_t)(edge_src + E)) + 15) & ~(uintptr_t)15);
  short* cWq  = wbase;            // 4 x 128x128 stacked -> 512x128
  short* cWk  = cWq  + 16384;
  short* cWv  = cWk  + 16384;
  short* cWsk = cWv  + 16384;
  short* cNgK = cWsk + 16384;     // 2 x 128x128 stacked -> 256x128
  short* cNgV = cNgK + 16384;
  short* cGnQ = cNgV + 16384;
  short* cGnO = cGnQ + 16384;
  short* cW1  = cGnO + 16384;     // 256x128
  short* cW2  = cW1  + 32768;     // 128x256

  float* outx   = (float*)d_out;
  float* outgh  = outx + ND;                       // 8192
  float* outreg = outgh + (size_t)Bb * NGT * D;    // 1
  float* wa     = outx;   // scratch fp32 N x 128

  const int GXM = (N + 127) / 128;    // 391
  const int SB  = (N + 1023) / 1024;  // 49
  dim3 blk256(256);

  // one-shot weight conversion + bias concat
  CvtArgs ca;
  ca.s[0] = Wq;   ca.d[0] = cWq;  ca.n[0] = 16384;
  ca.s[1] = Wk;   ca.d[1] = cWk;  ca.n[1] = 16384;
  ca.s[2] = Wv;   ca.d[2] = cWv;  ca.n[2] = 16384;
  ca.s[3] = Wsk;  ca.d[3] = cWsk; ca.n[3] = 16384;
  ca.s[4] = ngw + 128 * 128; ca.d[4] = cNgK; ca.n[4] = 16384;
  ca.s[5] = ngw + 256 * 128; ca.d[5] = cNgV; ca.n[5] = 16384;
  ca.s[6] = gnw;  ca.d[6] = cGnQ; ca.n[6] = 16384;
  ca.s[7] = gnow; ca.d[7] = cGnO; ca.n[7] = 16384;
  ca.s[8] = W1;   ca.d[8] = cW1;  ca.n[8] = 32768;
  ca.s[9] = W2;   ca.d[9] = cW2;  ca.n[9] = 32768;
  cvt_weights<<<dim3(32, 10), blk256, 0, stream>>>(ca);
  concat_bias4<<<dim3(1), dim3(128), 0, stream>>>(bqv, bkv, bvv, bsk, bias512);

  // CSR build
  hipMemsetAsync(deg, 0, (size_t)N * sizeof(int), stream);
  count_deg<<<dim3((E + 255) / 256), blk256, 0, stream>>>(dstI, deg, E);
  scan_pass1<<<dim3(SB), blk256, 0, stream>>>(deg, bsum, N);
  scan_pass2<<<dim3(1), dim3(1024), 0, stream>>>(bsum, SB);
  scan_pass3<<<dim3(SB), blk256, 0, stream>>>(deg, bsum, row_start, cursor, N, E);
  fill_edges<<<dim3((E + 255) / 256), blk256, 0, stream>>>(dstI, srcI, cursor, edge_src, E);

  // fused tconv projections (fp32 A, converted in-register): all 512 cols -> qkvb bf16
  gemm_direct<128, 1><<<dim3(GXM, 4), blk256, 0, stream>>>(x, cWq, bias512,
                                                           qkvb, 512, 512, nullptr, 0,
                                                           N, 512, 0);

  // edge attention + gate + LN  -> x1 (fp32) + x1b (bf16)
  tconv_attn<<<dim3((N * H + 255) / 256), blk256, 0, stream>>>(qkvb, row_start, edge_src, wa, N);
  gate_ln<<<dim3((N + 3) / 4), blk256, 0, stream>>>(x, wa, qkvb, Wbeta, x1, x1b, N);

  // global MHA: fused K|V projection (N x 256, bf16 out; aliases qkvb which is now dead)
  gemm_direct<128, 0><<<dim3(GXM, 2), blk256, 0, stream>>>(x1b, cNgK, ngb + 128,
                                                           kv16, 256, 256, nullptr, 0,
                                                           N, 256, 0);
  gemm_small<<<dim3(64), dim3(128), 0, stream>>>(gh, ngw, ngb, Qg, 64);
  glob_part<<<dim3(512, NCH), dim3(64), 0, stream>>>(Qg, kv16, Plog, pm, ps, pacc, MAXN);
  glob_merge<<<dim3(512), dim3(64), 0, stream>>>(pm, ps, pacc, Og, m_gl, is_gl);
  pker2<<<dim3((MAXN + 255) / 256, 8), blk256, 0, stream>>>(Plog, m_gl, is_gl, Pbuf, MAXN);
  regk<<<dim3(8), blk256, 0, stream>>>(Pbuf, offb, MAXN);
  regfin<<<dim3(1), dim3(64), 0, stream>>>(offb, outreg);

  gemm_small<<<dim3(64), dim3(128), 0, stream>>>(Og, ngow, ngob, gout, 64);
  ln_add<<<dim3(16), blk256, 0, stream>>>(gh, gout, outgh, nullptr, 64);   // new global_h

  // nodes attend to global tokens
  gemm_small<<<dim3(64), dim3(128), 0, stream>>>(outgh, gnw + 128 * 128, gnb + 128, Kg, 64);
  gemm_small<<<dim3(64), dim3(128), 0, stream>>>(outgh, gnw + 256 * 128, gnb + 256, Vg, 64);
  gemm_direct<128, 0><<<dim3(GXM, 1), blk256, 0, stream>>>(x1b, cGnQ, gnb,
                                                           Qnb, 128, 128, nullptr, 0,
                                                           N, 128, 0);   // Qn (bf16)
  node_attn<<<dim3((N + 31) / 32), blk256, 0, stream>>>(Qnb, Kg, Vg, Onb, N, MAXN);
  gemm_direct<128, 0><<<dim3(GXM, 1), blk256, 0, stream>>>(Onb, cGnO, gnob,
                                                           nullptr, 0, 0, wa, 128,
                                                           N, 128, 0);   // out proj (fp32)
  ln_add<<<dim3((N + 3) / 4), blk256, 0, stream>>>(x1, wa, x1, x1b, N);   // x2 fp32 + bf16

  // fused FF (64-row tiles) + final LN -> d_out x
  gemm_ff<<<dim3((N + 63) / 64), blk256, 0, stream>>>(x1b, cW1, b1v, cW2, b2v, ff2o, N);
  ln_add<<<dim3((N + 3) / 4), blk256, 0, stream>>>(x1, ff2o, outx, nullptr, N);
}

// Round 13
// 360.157 us; speedup vs baseline: 1.0712x; 1.0712x over previous
//
#include <hip/hip_runtime.h>
#include <math.h>

#define D 128
#define H 8
#define NGT 8
#define LSTOK 4   // n_global_tokens_global (fixed by problem)
#define NCH 4     // node chunks for glob_part

typedef short bf16x8 __attribute__((ext_vector_type(8)));
typedef float f32x4  __attribute__((ext_vector_type(4)));

__device__ __forceinline__ short f2bf(float f) {
  union { float f; unsigned u; } v; v.f = f;
  unsigned r = v.u + 0x7FFFu + ((v.u >> 16) & 1u);   // RNE
  return (short)(r >> 16);
}
__device__ __forceinline__ float bf2f(short s) {
  union { unsigned u; float f; } v;
  v.u = ((unsigned)(unsigned short)s) << 16;
  return v.f;
}
__device__ __forceinline__ float4 bf4(bf16x8 v, int lo) {
  return make_float4(bf2f(v[lo]), bf2f(v[lo + 1]), bf2f(v[lo + 2]), bf2f(v[lo + 3]));
}
__device__ __forceinline__ unsigned pk2(float a, float b) {
  return ((unsigned)(unsigned short)f2bf(b) << 16) | (unsigned short)f2bf(a);
}

__device__ __forceinline__ float dot4(float4 a, float4 b) {
  return a.x*b.x + a.y*b.y + a.z*b.z + a.w*b.w;
}
__device__ __forceinline__ float4 scale_madd(float4 a, float sc, float4 v, float p) {
  return make_float4(fmaf(p, v.x, a.x*sc), fmaf(p, v.y, a.y*sc),
                     fmaf(p, v.z, a.z*sc), fmaf(p, v.w, a.w*sc));
}
__device__ __forceinline__ float4 comb4(float4 a, float e1, float4 c, float e2) {
  return make_float4(a.x*e1 + c.x*e2, a.y*e1 + c.y*e2, a.z*e1 + c.z*e2, a.w*e1 + c.w*e2);
}
__device__ __forceinline__ float4 shfl_xor4(float4 v, int off) {
  return make_float4(__shfl_xor(v.x, off), __shfl_xor(v.y, off),
                     __shfl_xor(v.z, off), __shfl_xor(v.w, off));
}

// ---------------- weight fp32 -> bf16 conversion (one-shot, 10 matrices) ----------------
struct CvtArgs {
  const float* s[10];
  short*       d[10];
  int          n[10];
};

__global__ void cvt_weights(CvtArgs a) {
  int which = blockIdx.y;
  const float* s = a.s[which];
  short* d = a.d[which];
  int n = a.n[which];
  int i = (blockIdx.x * 256 + threadIdx.x) * 4;
  if (i + 3 < n) {
    float4 v = *(const float4*)(s + i);
    d[i]     = f2bf(v.x);
    d[i + 1] = f2bf(v.y);
    d[i + 2] = f2bf(v.z);
    d[i + 3] = f2bf(v.w);
  }
}

// x fp32 -> bf16 (n divisible by 8)
__global__ void cvt_x(const float* __restrict__ s, short* __restrict__ d, int n) {
  int i = (blockIdx.x * 256 + threadIdx.x) * 8;
  if (i + 7 < n) {
    float4 a = *(const float4*)(s + i);
    float4 b = *(const float4*)(s + i + 4);
    bf16x8 v;
    v[0] = f2bf(a.x); v[1] = f2bf(a.y); v[2] = f2bf(a.z); v[3] = f2bf(a.w);
    v[4] = f2bf(b.x); v[5] = f2bf(b.y); v[6] = f2bf(b.z); v[7] = f2bf(b.w);
    *(bf16x8*)(d + i) = v;
  }
}

__global__ void concat_bias4(const float* __restrict__ b0, const float* __restrict__ b1,
                             const float* __restrict__ b2, const float* __restrict__ b3,
                             float* __restrict__ out) {
  int t = threadIdx.x;
  out[t] = b0[t]; out[128 + t] = b1[t]; out[256 + t] = b2[t]; out[384 + t] = b3[t];
}

// ---------------- direct MFMA GEMM (no staging LDS; LDS only for bf16 epilogue) -------
#define EPST 72   // LDS epilogue row stride in shorts (144B, 16B-aligned)
template<int K>
__global__ void __launch_bounds__(256) gemm_direct(const short* __restrict__ A,
    const short* __restrict__ Wb, const float* __restrict__ bias,
    short* __restrict__ out16, int C16, int s16,
    float* __restrict__ out32, int s32,
    int Nrows, int Ccols, int relu)
{
  __shared__ short eplds[4][64 * EPST];
  const int t = threadIdx.x;
  const int wid = t >> 6, lane = t & 63;
  const int rowBase = blockIdx.x * 128 + (wid >> 1) * 64;
  const int colBase = blockIdx.y * 128 + (wid & 1) * 64;
  const int lrow = lane & 15;
  const int lk = (lane >> 4) * 8;

  f32x4 acc[4][4];
  f32x4 z4 = {0.f, 0.f, 0.f, 0.f};
#pragma unroll
  for (int m = 0; m < 4; m++)
#pragma unroll
    for (int n = 0; n < 4; n++) acc[m][n] = z4;

  const short* ap[4];
#pragma unroll
  for (int m = 0; m < 4; ++m) {
    int ar = rowBase + m * 16 + lrow;
    if (ar >= Nrows) ar = Nrows - 1;
    ap[m] = A + (size_t)ar * K + lk;
  }
  const short* wp[4];
#pragma unroll
  for (int n = 0; n < 4; ++n)
    wp[n] = Wb + (size_t)(colBase + n * 16 + lrow) * K + lk;

#pragma unroll
  for (int kb = 0; kb < K; kb += 32) {
    bf16x8 af[4], bfr[4];
#pragma unroll
    for (int m = 0; m < 4; ++m) af[m] = *(const bf16x8*)(ap[m] + kb);
#pragma unroll
    for (int n = 0; n < 4; ++n) bfr[n] = *(const bf16x8*)(wp[n] + kb);
#pragma unroll
    for (int m = 0; m < 4; ++m)
#pragma unroll
      for (int n = 0; n < 4; ++n)
        acc[m][n] = __builtin_amdgcn_mfma_f32_16x16x32_bf16(af[m], bfr[n], acc[m][n], 0, 0, 0);
  }

  const int ccol = lane & 15;
  const int rquad = (lane >> 4) * 4;
  if (colBase < C16) {
    short* lds = eplds[wid];
#pragma unroll
    for (int n = 0; n < 4; ++n) {
      float bb = bias[colBase + n * 16 + ccol];
      int col = n * 16 + ccol;
#pragma unroll
      for (int m = 0; m < 4; ++m) {
        int r0 = m * 16 + rquad;
#pragma unroll
        for (int r = 0; r < 4; ++r) {
          float v = acc[m][n][r] + bb;
          if (relu) v = fmaxf(v, 0.f);
          lds[(r0 + r) * EPST + col] = f2bf(v);
        }
      }
    }
    const int jr = lane >> 3, jc = lane & 7;
#pragma unroll
    for (int i = 0; i < 8; ++i) {
      int row = i * 8 + jr;
      int gr = rowBase + row;
      if (gr < Nrows) {
        bf16x8 v = *(const bf16x8*)(lds + row * EPST + jc * 8);
        *(bf16x8*)(out16 + (size_t)gr * s16 + colBase + jc * 8) = v;
      }
    }
  } else {
#pragma unroll
    for (int n = 0; n < 4; ++n) {
      int col = colBase + n * 16 + ccol;
      float bb = bias[col];
#pragma unroll
      for (int m = 0; m < 4; ++m) {
        int row0 = rowBase + m * 16 + rquad;
#pragma unroll
        for (int r = 0; r < 4; ++r) {
          int gr = row0 + r;
          if (gr < Nrows) {
            float v = acc[m][n][r] + bb;
            if (relu) v = fmaxf(v, 0.f);
            out32[(size_t)gr * s32 + (col - C16)] = v;
          }
        }
      }
    }
  }
}

// ---------------- fused FF: out = relu(A@W1^T+b1)@W2^T+b2 (ff1 via LDS) ----------------
#define FFST 264   // LDS row stride in shorts for the 256-wide ff1 tile
__global__ void __launch_bounds__(256) gemm_ff(const short* __restrict__ A,
    const short* __restrict__ W1b, const float* __restrict__ b1,
    const short* __restrict__ W2b, const float* __restrict__ b2,
    float* __restrict__ out, int Nrows)
{
  __shared__ short flds[128 * FFST];
  const int t = threadIdx.x;
  const int wid = t >> 6, lane = t & 63;
  const int rowL = (wid >> 1) * 64;
  const int rowBase = blockIdx.x * 128 + rowL;
  const int lrow = lane & 15;
  const int lk = (lane >> 4) * 8;
  const int ccol = lane & 15;
  const int rquad = (lane >> 4) * 4;
  f32x4 z4 = {0.f, 0.f, 0.f, 0.f};

  const short* ap[4];
#pragma unroll
  for (int m = 0; m < 4; ++m) {
    int ar = rowBase + m * 16 + lrow;
    if (ar >= Nrows) ar = Nrows - 1;
    ap[m] = A + (size_t)ar * 128 + lk;
  }

  // ---- stage A: ff1 tile (128x256) in two 128-col passes -> LDS bf16 (relu'd) ----
  for (int cb = 0; cb < 2; ++cb) {
    int colBase = cb * 128 + (wid & 1) * 64;
    f32x4 acc[4][4];
#pragma unroll
    for (int m = 0; m < 4; m++)
#pragma unroll
      for (int n = 0; n < 4; n++) acc[m][n] = z4;
    const short* wp[4];
#pragma unroll
    for (int n = 0; n < 4; ++n)
      wp[n] = W1b + (size_t)(colBase + n * 16 + lrow) * 128 + lk;
#pragma unroll
    for (int kb = 0; kb < 128; kb += 32) {
      bf16x8 af[4], bfr[4];
#pragma unroll
      for (int m = 0; m < 4; ++m) af[m] = *(const bf16x8*)(ap[m] + kb);
#pragma unroll
      for (int n = 0; n < 4; ++n) bfr[n] = *(const bf16x8*)(wp[n] + kb);
#pragma unroll
      for (int m = 0; m < 4; ++m)
#pragma unroll
        for (int n = 0; n < 4; ++n)
          acc[m][n] = __builtin_amdgcn_mfma_f32_16x16x32_bf16(af[m], bfr[n], acc[m][n], 0, 0, 0);
    }
#pragma unroll
    for (int n = 0; n < 4; ++n) {
      int col = colBase + n * 16 + ccol;
      float bb = b1[col];
#pragma unroll
      for (int m = 0; m < 4; ++m) {
        int r0 = rowL + m * 16 + rquad;
#pragma unroll
        for (int r = 0; r < 4; ++r) {
          float v = fmaxf(acc[m][n][r] + bb, 0.f);
          flds[(r0 + r) * FFST + col] = f2bf(v);
        }
      }
    }
  }
  __syncthreads();

  // ---- stage B: out(128x128) = ff1 @ W2^T + b2, K=256, A from LDS ----
  {
    int colBase = (wid & 1) * 64;
    f32x4 acc[4][4];
#pragma unroll
    for (int m = 0; m < 4; m++)
#pragma unroll
      for (int n = 0; n < 4; n++) acc[m][n] = z4;
    const short* wp[4];
#pragma unroll
    for (int n = 0; n < 4; ++n)
      wp[n] = W2b + (size_t)(colBase + n * 16 + lrow) * 256 + lk;
#pragma unroll
    for (int kb = 0; kb < 256; kb += 32) {
      bf16x8 af[4], bfr[4];
#pragma unroll
      for (int m = 0; m < 4; ++m)
        af[m] = *(const bf16x8*)(flds + (rowL + m * 16 + lrow) * FFST + kb + lk);
#pragma unroll
      for (int n = 0; n < 4; ++n) bfr[n] = *(const bf16x8*)(wp[n] + kb);
#pragma unroll
      for (int m = 0; m < 4; ++m)
#pragma unroll
        for (int n = 0; n < 4; ++n)
          acc[m][n] = __builtin_amdgcn_mfma_f32_16x16x32_bf16(af[m], bfr[n], acc[m][n], 0, 0, 0);
    }
#pragma unroll
    for (int n = 0; n < 4; ++n) {
      int col = colBase + n * 16 + ccol;
      float bb = b2[col];
#pragma unroll
      for (int m = 0; m < 4; ++m) {
        int row0 = rowBase + m * 16 + rquad;
#pragma unroll
        for (int r = 0; r < 4; ++r) {
          int gr = row0 + r;
          if (gr < Nrows) out[(size_t)gr * 128 + col] = acc[m][n][r] + bb;
        }
      }
    }
  }
}

// ------- fused node path: Q=A@GnQ^T+b -> 8-token attention -> On@GnO^T+b -> out -------
#define QST 136
__global__ void __launch_bounds__(256) gemm_node(const short* __restrict__ A,
    const short* __restrict__ GnQb, const float* __restrict__ gnbq,
    const float* __restrict__ Kg, const float* __restrict__ Vg,
    const short* __restrict__ GnOb, const float* __restrict__ gnbo,
    float* __restrict__ out, int Nrows, int MAXN)
{
  __shared__ short qlds[128 * QST];
  __shared__ float kg[2][NGT * 128];
  __shared__ float vg[2][NGT * 128];
  const int t = threadIdx.x;
  const int wid = t >> 6, lane = t & 63;
  const int rowL = (wid >> 1) * 64;
  const int n0 = blockIdx.x * 128;
  const int rowBase = n0 + rowL;
  const int colBase = (wid & 1) * 64;
  const int lrow = lane & 15;
  const int lk = (lane >> 4) * 8;
  const int ccol = lane & 15;
  const int rquad = (lane >> 4) * 4;
  f32x4 z4 = {0.f, 0.f, 0.f, 0.f};

  // stage K/V for the (up to 2) batches this block touches
  int b0 = n0 / MAXN;
  int nlast = n0 + 127; if (nlast >= Nrows) nlast = Nrows - 1;
  int bLast = nlast / MAXN;
  int nb = (bLast != b0) ? 2 : 1;
  for (int bi = 0; bi < nb; ++bi) {
    size_t gb = (size_t)((b0 + bi) * NGT) * 128;
    int i = t * 4;
    *(float4*)&kg[bi][i] = *(const float4*)(Kg + gb + i);
    *(float4*)&vg[bi][i] = *(const float4*)(Vg + gb + i);
  }

  // ---- stage A: Q tile = A @ GnQ^T + bias -> qlds bf16 ----
  {
    f32x4 acc[4][4];
#pragma unroll
    for (int m = 0; m < 4; m++)
#pragma unroll
      for (int n = 0; n < 4; n++) acc[m][n] = z4;
    const short* ap[4];
#pragma unroll
    for (int m = 0; m < 4; ++m) {
      int ar = rowBase + m * 16 + lrow;
      if (ar >= Nrows) ar = Nrows - 1;
      ap[m] = A + (size_t)ar * 128 + lk;
    }
    const short* wp[4];
#pragma unroll
    for (int n = 0; n < 4; ++n)
      wp[n] = GnQb + (size_t)(colBase + n * 16 + lrow) * 128 + lk;
#pragma unroll
    for (int kb = 0; kb < 128; kb += 32) {
      bf16x8 af[4], bfr[4];
#pragma unroll
      for (int m = 0; m < 4; ++m) af[m] = *(const bf16x8*)(ap[m] + kb);
#pragma unroll
      for (int n = 0; n < 4; ++n) bfr[n] = *(const bf16x8*)(wp[n] + kb);
#pragma unroll
      for (int m = 0; m < 4; ++m)
#pragma unroll
        for (int n = 0; n < 4; ++n)
          acc[m][n] = __builtin_amdgcn_mfma_f32_16x16x32_bf16(af[m], bfr[n], acc[m][n], 0, 0, 0);
    }
#pragma unroll
    for (int n = 0; n < 4; ++n) {
      int col = colBase + n * 16 + ccol;
      float bb = gnbq[col];
#pragma unroll
      for (int m = 0; m < 4; ++m) {
        int r0 = rowL + m * 16 + rquad;
#pragma unroll
        for (int r = 0; r < 4; ++r)
          qlds[(r0 + r) * QST + col] = f2bf(acc[m][n][r] + bb);
      }
    }
  }
  __syncthreads();

  // ---- stage B: per-(row,h) attention over 8 tokens; On overwrites Q slot ----
#pragma unroll
  for (int u = 0; u < 4; ++u) {
    int unit = t + u * 256;            // 0..1023
    int row = unit >> 3, h = unit & 7;
    int grow = n0 + row;
    if (grow < Nrows) {
      int bi = (grow / MAXN) - b0;
      short* qp = qlds + row * QST + h * 16;
      bf16x8 qa = *(const bf16x8*)(qp);
      bf16x8 qb = *(const bf16x8*)(qp + 8);
      float4 q0 = bf4(qa, 0), q1 = bf4(qa, 4), q2 = bf4(qb, 0), q3 = bf4(qb, 4);
      float l[NGT];
      float mx = -3.0e38f;
#pragma unroll
      for (int tk = 0; tk < NGT; tk++) {
        const float4* k4 = (const float4*)(&kg[bi][tk * 128 + h * 16]);
        float d = dot4(q0, k4[0]) + dot4(q1, k4[1]) + dot4(q2, k4[2]) + dot4(q3, k4[3]);
        l[tk] = d * 0.25f;
        mx = fmaxf(mx, l[tk]);
      }
      float s = 0.f;
#pragma unroll
      for (int tk = 0; tk < NGT; tk++) { l[tk] = expf(l[tk] - mx); s += l[tk]; }
      float inv = 1.f / s;
      float4 a0 = make_float4(0, 0, 0, 0), a1 = a0, a2 = a0, a3 = a0;
#pragma unroll
      for (int tk = 0; tk < NGT; tk++) {
        float p = l[tk] * inv;
        const float4* v4 = (const float4*)(&vg[bi][tk * 128 + h * 16]);
        a0 = scale_madd(a0, 1.f, v4[0], p);
        a1 = scale_madd(a1, 1.f, v4[1], p);
        a2 = scale_madd(a2, 1.f, v4[2], p);
        a3 = scale_madd(a3, 1.f, v4[3], p);
      }
      unsigned* o = (unsigned*)qp;
      o[0] = pk2(a0.x, a0.y); o[1] = pk2(a0.z, a0.w);
      o[2] = pk2(a1.x, a1.y); o[3] = pk2(a1.z, a1.w);
      o[4] = pk2(a2.x, a2.y); o[5] = pk2(a2.z, a2.w);
      o[6] = pk2(a3.x, a3.y); o[7] = pk2(a3.z, a3.w);
    }
  }
  __syncthreads();

  // ---- stage C: out = On @ GnO^T + bias (fp32, coalesced) ----
  {
    f32x4 acc[4][4];
#pragma unroll
    for (int m = 0; m < 4; m++)
#pragma unroll
      for (int n = 0; n < 4; n++) acc[m][n] = z4;
    const short* wp[4];
#pragma unroll
    for (int n = 0; n < 4; ++n)
      wp[n] = GnOb + (size_t)(colBase + n * 16 + lrow) * 128 + lk;
#pragma unroll
    for (int kb = 0; kb < 128; kb += 32) {
      bf16x8 af[4], bfr[4];
#pragma unroll
      for (int m = 0; m < 4; ++m)
        af[m] = *(const bf16x8*)(qlds + (rowL + m * 16 + lrow) * QST + kb + lk);
#pragma unroll
      for (int n = 0; n < 4; ++n) bfr[n] = *(const bf16x8*)(wp[n] + kb);
#pragma unroll
      for (int m = 0; m < 4; ++m)
#pragma unroll
        for (int n = 0; n < 4; ++n)
          acc[m][n] = __builtin_amdgcn_mfma_f32_16x16x32_bf16(af[m], bfr[n], acc[m][n], 0, 0, 0);
    }
#pragma unroll
    for (int n = 0; n < 4; ++n) {
      int col = colBase + n * 16 + ccol;
      float bb = gnbo[col];
#pragma unroll
      for (int m = 0; m < 4; ++m) {
        int row0 = rowBase + m * 16 + rquad;
#pragma unroll
        for (int r = 0; r < 4; ++r) {
          int gr = row0 + r;
          if (gr < Nrows) out[(size_t)gr * 128 + col] = acc[m][n][r] + bb;
        }
      }
    }
  }
}

// small GEMM (M rows <= 64, K=C=128): one block per row
__global__ void gemm_small(const float* __restrict__ A, const float* __restrict__ W,
                           const float* __restrict__ bias, float* __restrict__ out, int M)
{
  int r = blockIdx.x;
  int c = threadIdx.x;
  __shared__ float as[128];
  as[c] = A[(size_t)r * 128 + c];
  __syncthreads();
  float acc = bias[c];
  const float* wr = W + (size_t)c * 128;
#pragma unroll 4
  for (int k = 0; k < 128; k++) acc += as[k] * wr[k];
  out[(size_t)r * 128 + c] = acc;
}

// ---------------- CSR build ----------------
__global__ void count_deg(const int* __restrict__ dst, int* __restrict__ deg, int E) {
  int e = blockIdx.x * 256 + threadIdx.x;
  if (e < E) atomicAdd(&deg[dst[e]], 1);
}

__global__ void scan_pass1(const int* __restrict__ deg, int* __restrict__ bsum, int N) {
  int t = threadIdx.x, lane = t & 63, wid = t >> 6;
  int idx = blockIdx.x * 1024 + t * 4;
  int4 v = {0, 0, 0, 0};
  if (idx + 3 < N) v = *(const int4*)(deg + idx);
  else {
    if (idx < N) v.x = deg[idx];
    if (idx + 1 < N) v.y = deg[idx + 1];
    if (idx + 2 < N) v.z = deg[idx + 2];
    if (idx + 3 < N) v.w = deg[idx + 3];
  }
  int s = v.x + v.y + v.z + v.w;
#pragma unroll
  for (int off = 32; off >= 1; off >>= 1) s += __shfl_xor(s, off);
  __shared__ int ws[4];
  if (lane == 0) ws[wid] = s;
  __syncthreads();
  if (t == 0) bsum[blockIdx.x] = ws[0] + ws[1] + ws[2] + ws[3];
}

__global__ void scan_pass2(int* __restrict__ bsum, int SB) {
  __shared__ int sh[1024];
  int t = threadIdx.x;
  sh[t] = (t < SB) ? bsum[t] : 0;
  __syncthreads();
  for (int off = 1; off < 1024; off <<= 1) {
    int v = (t >= off) ? sh[t - off] : 0;
    __syncthreads();
    sh[t] += v;
    __syncthreads();
  }
  if (t < SB) bsum[t] = (t == 0) ? 0 : sh[t - 1];
}

__global__ void scan_pass3(const int* __restrict__ deg, const int* __restrict__ bsum,
                           int* __restrict__ row_start, int* __restrict__ cursor,
                           int N, int E)
{
  int t = threadIdx.x, lane = t & 63, wid = t >> 6;
  int idx = blockIdx.x * 1024 + t * 4;
  int4 v = {0, 0, 0, 0};
  if (idx + 3 < N) v = *(const int4*)(deg + idx);
  else {
    if (idx < N) v.x = deg[idx];
    if (idx + 1 < N) v.y = deg[idx + 1];
    if (idx + 2 < N) v.z = deg[idx + 2];
    if (idx + 3 < N) v.w = deg[idx + 3];
  }
  int ts = v.x + v.y + v.z + v.w;
  int x = ts;
#pragma unroll
  for (int off = 1; off < 64; off <<= 1) {
    int y = __shfl_up(x, off);
    if (lane >= off) x += y;
  }
  __shared__ int ws[4];
  if (lane == 63) ws[wid] = x;
  __syncthreads();
  int woff = 0;
  for (int i = 0; i < wid; i++) woff += ws[i];
  int p = bsum[blockIdx.x] + woff + (x - ts);
  if (idx < N)     { row_start[idx] = p; cursor[idx] = p; }     p += v.x;
  if (idx + 1 < N) { row_start[idx + 1] = p; cursor[idx + 1] = p; } p += v.y;
  if (idx + 2 < N) { row_start[idx + 2] = p; cursor[idx + 2] = p; } p += v.z;
  if (idx + 3 < N) { row_start[idx + 3] = p; cursor[idx + 3] = p; }
  if (blockIdx.x == 0 && t == 0) row_start[N] = E;
}

__global__ void fill_edges(const int* __restrict__ dst, const int* __restrict__ src,
                           int* __restrict__ cursor, int* __restrict__ edge_src, int E) {
  int e = blockIdx.x * 256 + threadIdx.x;
  if (e < E) {
    int p = atomicAdd(&cursor[dst[e]], 1);
    edge_src[p] = src[e];
  }
}

// ---------------- tconv edge attention: q|k|v|xr bf16 (qkvb stride 512) ----------------
__global__ void tconv_attn(const short* __restrict__ qkvb,
                           const int* __restrict__ row_start,
                           const int* __restrict__ edge_src,
                           float* __restrict__ out, int N)
{
  int gid = blockIdx.x * 256 + threadIdx.x;
  if (gid >= N * H) return;
  int n = gid >> 3, h = gid & 7;
  const short* qp = qkvb + (size_t)n * 512 + h * 16;
  bf16x8 qa = *(const bf16x8*)(qp);
  bf16x8 qb = *(const bf16x8*)(qp + 8);
  float4 q0 = bf4(qa, 0), q1 = bf4(qa, 4), q2 = bf4(qb, 0), q3 = bf4(qb, 4);
  int e0 = row_start[n], e1 = row_start[n + 1];

  float mA = -3.0e38f, sA = 0.f;
  float4 A0 = make_float4(0, 0, 0, 0), A1 = A0, A2 = A0, A3 = A0;
  float mB = -3.0e38f, sB = 0.f;
  float4 B0 = A0, B1 = A0, B2 = A0, B3 = A0;

  int ei = e0;
  for (; ei + 1 < e1; ei += 2) {
    int sn0 = edge_src[ei], sn1 = edge_src[ei + 1];
    const short* kp0 = qkvb + (size_t)sn0 * 512 + 128 + h * 16;
    const short* kp1 = qkvb + (size_t)sn1 * 512 + 128 + h * 16;
    bf16x8 k00 = *(const bf16x8*)(kp0);
    bf16x8 k01 = *(const bf16x8*)(kp0 + 8);
    bf16x8 k10 = *(const bf16x8*)(kp1);
    bf16x8 k11 = *(const bf16x8*)(kp1 + 8);
    float d0 = (dot4(q0, bf4(k00, 0)) + dot4(q1, bf4(k00, 4))
              + dot4(q2, bf4(k01, 0)) + dot4(q3, bf4(k01, 4))) * 0.25f;
    float d1 = (dot4(q0, bf4(k10, 0)) + dot4(q1, bf4(k10, 4))
              + dot4(q2, bf4(k11, 0)) + dot4(q3, bf4(k11, 4))) * 0.25f;
    bf16x8 v00 = *(const bf16x8*)(kp0 + 128);
    bf16x8 v01 = *(const bf16x8*)(kp0 + 136);
    bf16x8 v10 = *(const bf16x8*)(kp1 + 128);
    bf16x8 v11 = *(const bf16x8*)(kp1 + 136);
    float mn0 = fmaxf(mA, d0);
    float sc0 = expf(mA - mn0), p0 = expf(d0 - mn0);
    A0 = scale_madd(A0, sc0, bf4(v00, 0), p0);
    A1 = scale_madd(A1, sc0, bf4(v00, 4), p0);
    A2 = scale_madd(A2, sc0, bf4(v01, 0), p0);
    A3 = scale_madd(A3, sc0, bf4(v01, 4), p0);
    sA = sA * sc0 + p0; mA = mn0;
    float mn1 = fmaxf(mB, d1);
    float sc1 = expf(mB - mn1), p1 = expf(d1 - mn1);
    B0 = scale_madd(B0, sc1, bf4(v10, 0), p1);
    B1 = scale_madd(B1, sc1, bf4(v10, 4), p1);
    B2 = scale_madd(B2, sc1, bf4(v11, 0), p1);
    B3 = scale_madd(B3, sc1, bf4(v11, 4), p1);
    sB = sB * sc1 + p1; mB = mn1;
  }
  if (ei < e1) {
    int sn0 = edge_src[ei];
    const short* kp0 = qkvb + (size_t)sn0 * 512 + 128 + h * 16;
    bf16x8 k00 = *(const bf16x8*)(kp0);
    bf16x8 k01 = *(const bf16x8*)(kp0 + 8);
    float d0 = (dot4(q0, bf4(k00, 0)) + dot4(q1, bf4(k00, 4))
              + dot4(q2, bf4(k01, 0)) + dot4(q3, bf4(k01, 4))) * 0.25f;
    bf16x8 v00 = *(const bf16x8*)(kp0 + 128);
    bf16x8 v01 = *(const bf16x8*)(kp0 + 136);
    float mn0 = fmaxf(mA, d0);
    float sc0 = expf(mA - mn0), p0 = expf(d0 - mn0);
    A0 = scale_madd(A0, sc0, bf4(v00, 0), p0);
    A1 = scale_madd(A1, sc0, bf4(v00, 4), p0);
    A2 = scale_madd(A2, sc0, bf4(v01, 0), p0);
    A3 = scale_madd(A3, sc0, bf4(v01, 4), p0);
    sA = sA * sc0 + p0; mA = mn0;
  }
  float mn = fmaxf(mA, mB);
  float eA = expf(mA - mn), eB = expf(mB - mn);
  float s = sA * eA + sB * eB;
  float4 a0 = comb4(A0, eA, B0, eB);
  float4 a1 = comb4(A1, eA, B1, eB);
  float4 a2 = comb4(A2, eA, B2, eB);
  float4 a3 = comb4(A3, eA, B3, eB);
  float inv = 1.f / (s + 1e-16f);
  float4* o4 = (float4*)(out + (size_t)n * 128 + h * 16);
  o4[0] = make_float4(a0.x * inv, a0.y * inv, a0.z * inv, a0.w * inv);
  o4[1] = make_float4(a1.x * inv, a1.y * inv, a1.z * inv, a1.w * inv);
  o4[2] = make_float4(a2.x * inv, a2.y * inv, a2.z * inv, a2.w * inv);
  o4[3] = make_float4(a3.x * inv, a3.y * inv, a3.z * inv, a3.w * inv);
}

// ---------------- gate + residual + LN -> x1 (fp32) + x1b (bf16); xr bf16 in qkvb ------
__global__ void gate_ln(const float* __restrict__ x, const float* __restrict__ att,
                        const short* __restrict__ qkvb, const float* __restrict__ Wb,
                        float* __restrict__ x1, short* __restrict__ x1b, int N)
{
  int wid = threadIdx.x >> 6, lane = threadIdx.x & 63;
  int n = blockIdx.x * 4 + wid;
  if (n >= N) return;
  size_t base = (size_t)n * 128 + lane * 2;
  float2 o = *(const float2*)(att + base);
  unsigned ru = *(const unsigned*)(qkvb + (size_t)n * 512 + 384 + lane * 2);
  float2 r = make_float2(bf2f((short)(ru & 0xFFFF)), bf2f((short)(ru >> 16)));
  float2 xv = *(const float2*)(x + base);
  float2 w0 = *(const float2*)(Wb + lane * 2);
  float2 w1 = *(const float2*)(Wb + 128 + lane * 2);
  float2 w2 = *(const float2*)(Wb + 256 + lane * 2);
  float ts = o.x * w0.x + o.y * w0.y + r.x * w1.x + r.y * w1.y
           + (o.x - r.x) * w2.x + (o.y - r.y) * w2.y;
#pragma unroll
  for (int mm = 32; mm >= 1; mm >>= 1) ts += __shfl_xor(ts, mm);
  float beta = 1.f / (1.f + expf(-ts));
  float2 y;
  y.x = xv.x + beta * r.x + (1.f - beta) * o.x;
  y.y = xv.y + beta * r.y + (1.f - beta) * o.y;
  float sm = y.x + y.y;
#pragma unroll
  for (int mm = 32; mm >= 1; mm >>= 1) sm += __shfl_xor(sm, mm);
  float mean = sm * (1.f / 128.f);
  float dx = y.x - mean, dy = y.y - mean;
  float vs = dx * dx + dy * dy;
#pragma unroll
  for (int mm = 32; mm >= 1; mm >>= 1) vs += __shfl_xor(vs, mm);
  float rstd = rsqrtf(vs * (1.f / 128.f) + 1e-5f);
  float ox = dx * rstd, oy = dy * rstd;
  *(float2*)(x1 + base) = make_float2(ox, oy);
  *(unsigned*)(x1b + base) = pk2(ox, oy);
}

// ---------------- out = LN(a + b); optional bf16 copy ----------------
__global__ void ln_add(const float* __restrict__ a, const float* __restrict__ b,
                       float* __restrict__ out, short* __restrict__ out16, int R)
{
  int wid = threadIdx.x >> 6, lane = threadIdx.x & 63;
  int r = blockIdx.x * 4 + wid;
  if (r >= R) return;
  size_t base = (size_t)r * 128 + lane * 2;
  float2 av = *(const float2*)(a + base);
  float2 bv = *(const float2*)(b + base);
  float2 y = make_float2(av.x + bv.x, av.y + bv.y);
  float sm = y.x + y.y;
#pragma unroll
  for (int mm = 32; mm >= 1; mm >>= 1) sm += __shfl_xor(sm, mm);
  float mean = sm * (1.f / 128.f);
  float dx = y.x - mean, dy = y.y - mean;
  float vs = dx * dx + dy * dy;
#pragma unroll
  for (int mm = 32; mm >= 1; mm >>= 1) vs += __shfl_xor(vs, mm);
  float rstd = rsqrtf(vs * (1.f / 128.f) + 1e-5f);
  float ox = dx * rstd, oy = dy * rstd;
  *(float2*)(out + base) = make_float2(ox, oy);
  if (out16) *(unsigned*)(out16 + base) = pk2(ox, oy);
}

// ---------------- glob attention, pass 1: partial online softmax over node chunks ------
__global__ void glob_part(const float* __restrict__ Qg, const short* __restrict__ kv,
                          float* __restrict__ Plog,
                          float* __restrict__ pm, float* __restrict__ ps,
                          float* __restrict__ pacc, int MAXN)
{
  int blk = blockIdx.x;                 // b*64 + g*8 + h
  int ch = blockIdx.y;
  int h = blk & 7, g = (blk >> 3) & 7, b = blk >> 6;
  int lane = threadIdx.x;
  const float4* q4 = (const float4*)(Qg + (size_t)(b * NGT + g) * 128 + h * 16);
  float4 q0 = q4[0], q1 = q4[1], q2 = q4[2], q3 = q4[3];
  int chunk = (MAXN + NCH - 1) / NCH;
  int n0 = ch * chunk;
  int n1 = n0 + chunk; if (n1 > MAXN) n1 = MAXN;
  float* plrow = (g >= LSTOK) ? Plog + (((size_t)(b * 4 + g - LSTOK)) * H + h) * MAXN : nullptr;
  float m = -3.0e38f, s = 0.f;
  float4 a0 = make_float4(0, 0, 0, 0), a1 = a0, a2 = a0, a3 = a0;
  for (int n = n0 + lane; n < n1; n += 64) {
    const short* kp = kv + ((size_t)(b * MAXN + n)) * 256 + h * 16;
    bf16x8 k0 = *(const bf16x8*)(kp);
    bf16x8 k1 = *(const bf16x8*)(kp + 8);
    float d = dot4(q0, bf4(k0, 0)) + dot4(q1, bf4(k0, 4))
            + dot4(q2, bf4(k1, 0)) + dot4(q3, bf4(k1, 4));
    d *= 0.25f;
    if (plrow) plrow[n] = d;
    float mn = fmaxf(m, d);
    float sc = expf(m - mn);
    float p = expf(d - mn);
    bf16x8 v0 = *(const bf16x8*)(kp + 128);
    bf16x8 v1 = *(const bf16x8*)(kp + 136);
    a0 = scale_madd(a0, sc, bf4(v0, 0), p);
    a1 = scale_madd(a1, sc, bf4(v0, 4), p);
    a2 = scale_madd(a2, sc, bf4(v1, 0), p);
    a3 = scale_madd(a3, sc, bf4(v1, 4), p);
    s = s * sc + p;
    m = mn;
  }
#pragma unroll
  for (int off = 32; off >= 1; off >>= 1) {
    float m2 = __shfl_xor(m, off);
    float s2 = __shfl_xor(s, off);
    float4 c0 = shfl_xor4(a0, off), c1 = shfl_xor4(a1, off);
    float4 c2 = shfl_xor4(a2, off), c3 = shfl_xor4(a3, off);
    float mn = fmaxf(m, m2);
    float e1 = expf(m - mn), e2 = expf(m2 - mn);
    s = s * e1 + s2 * e2;
    a0 = comb4(a0, e1, c0, e2);
    a1 = comb4(a1, e1, c1, e2);
    a2 = comb4(a2, e1, c2, e2);
    a3 = comb4(a3, e1, c3, e2);
    m = mn;
  }
  if (lane == 0) {
    int pi = blk * NCH + ch;
    pm[pi] = m; ps[pi] = s;
    float4* pa = (float4*)(pacc + (size_t)pi * 16);
    pa[0] = a0; pa[1] = a1; pa[2] = a2; pa[3] = a3;
  }
}

__global__ void glob_merge(const float* __restrict__ pm, const float* __restrict__ ps,
                           const float* __restrict__ pacc, float* __restrict__ Og,
                           float* __restrict__ m_gl, float* __restrict__ is_gl)
{
  int blk = blockIdx.x;
  int lane = threadIdx.x;
  float m = -3.0e38f;
#pragma unroll
  for (int c = 0; c < NCH; ++c) m = fmaxf(m, pm[blk * NCH + c]);
  float s = 0.f;
#pragma unroll
  for (int c = 0; c < NCH; ++c) s += ps[blk * NCH + c] * expf(pm[blk * NCH + c] - m);
  if (lane < 16) {
    float a = 0.f;
#pragma unroll
    for (int c = 0; c < NCH; ++c)
      a += pacc[(size_t)(blk * NCH + c) * 16 + lane] * expf(pm[blk * NCH + c] - m);
    int h = blk & 7, g = (blk >> 3) & 7, b = blk >> 6;
    Og[(size_t)(b * NGT + g) * 128 + h * 16 + lane] = a / s;
  }
  if (lane == 0) { m_gl[blk] = m; is_gl[blk] = 1.f / s; }
}

// ---------------- P rows from stored logits ----------------
__global__ void pker2(const float* __restrict__ Plog,
                      const float* __restrict__ m_gl, const float* __restrict__ is_gl,
                      float* __restrict__ P, int MAXN)
{
  int b = blockIdx.y;
  __shared__ float ms[32], iss[32];
  if (threadIdx.x < 32) {
    int g = threadIdx.x >> 3, h = threadIdx.x & 7;
    ms[threadIdx.x]  = m_gl[(b * NGT + LSTOK + g) * H + h];
    iss[threadIdx.x] = is_gl[(b * NGT + LSTOK + g) * H + h];
  }
  __syncthreads();
  int n = blockIdx.x * 256 + threadIdx.x;
  if (n >= MAXN) return;
#pragma unroll
  for (int g = 0; g < 4; g++) {
    float acc = 0.f;
#pragma unroll
    for (int h = 0; h < H; h++) {
      float l = Plog[(((size_t)(b * 4 + g)) * H + h) * MAXN + n];
      acc += expf(l - ms[g * 8 + h]) * iss[g * 8 + h];
    }
    P[(size_t)(b * 4 + g) * MAXN + n] = acc * 0.125f;
  }
}

// ---------------- reg: off-diagonal Gram of row-normalized P ----------------
__global__ void regk(const float* __restrict__ P, float* __restrict__ offb, int MAXN)
{
  int b = blockIdx.x;
  int t = threadIdx.x;
  float v[10];
#pragma unroll
  for (int i = 0; i < 10; i++) v[i] = 0.f;
  for (int n = t; n < MAXN; n += 256) {
    float p0 = P[(size_t)(b * 4 + 0) * MAXN + n];
    float p1 = P[(size_t)(b * 4 + 1) * MAXN + n];
    float p2 = P[(size_t)(b * 4 + 2) * MAXN + n];
    float p3 = P[(size_t)(b * 4 + 3) * MAXN + n];
    v[0] += p0; v[1] += p1; v[2] += p2; v[3] += p3;
    v[4] += p0 * p1; v[5] += p0 * p2; v[6] += p0 * p3;
    v[7] += p1 * p2; v[8] += p1 * p3; v[9] += p2 * p3;
  }
#pragma unroll
  for (int i = 0; i < 10; i++) {
    float x = v[i];
#pragma unroll
    for (int mm = 32; mm >= 1; mm >>= 1) x += __shfl_xor(x, mm);
    v[i] = x;
  }
  __shared__ float red[4][10];
  int wid = t >> 6, lane = t & 63;
  if (lane == 0)
    for (int i = 0; i < 10; i++) red[wid][i] = v[i];
  __syncthreads();
  if (t == 0) {
    float r[10];
    for (int i = 0; i < 10; i++) r[i] = red[0][i] + red[1][i] + red[2][i] + red[3][i];
    float r0 = r[0] + 1e-8f, r1 = r[1] + 1e-8f, r2 = r[2] + 1e-8f, r3 = r[3] + 1e-8f;
    float off = 2.f * (r[4] / (r0 * r1) + r[5] / (r0 * r2) + r[6] / (r0 * r3)
                     + r[7] / (r1 * r2) + r[8] / (r1 * r3) + r[9] / (r2 * r3));
    offb[b] = off * (1.f / 12.f);   // (Kt*Kt - Kt) = 12
  }
}

__global__ void regfin(const float* __restrict__ offb, float* __restrict__ out) {
  if (threadIdx.x == 0 && blockIdx.x == 0) {
    float s = 0.f;
    for (int i = 0; i < 8; i++) s += offb[i];
    *out = s * (1.f / 8.f);
  }
}

extern "C" void kernel_launch(void* const* d_in, const int* in_sizes, int n_in,
                              void* d_out, int out_size, void* d_ws, size_t ws_size,
                              hipStream_t stream)
{
  const float* x     = (const float*)d_in[0];
  const int*   ei    = (const int*)d_in[1];
  const float* gh    = (const float*)d_in[2];
  const float* Wq    = (const float*)d_in[6];
  const float* bqv   = (const float*)d_in[7];
  const float* Wk    = (const float*)d_in[8];
  const float* bkv   = (const float*)d_in[9];
  const float* Wv    = (const float*)d_in[10];
  const float* bvv   = (const float*)d_in[11];
  const float* Wsk   = (const float*)d_in[12];
  const float* bsk   = (const float*)d_in[13];
  const float* Wbeta = (const float*)d_in[14];
  const float* ngw   = (const float*)d_in[15];
  const float* ngb   = (const float*)d_in[16];
  const float* ngow  = (const float*)d_in[17];
  const float* ngob  = (const float*)d_in[18];
  const float* gnw   = (const float*)d_in[19];
  const float* gnb   = (const float*)d_in[20];
  const float* gnow  = (const float*)d_in[21];
  const float* gnob  = (const float*)d_in[22];
  const float* W1    = (const float*)d_in[23];
  const float* b1v   = (const float*)d_in[24];
  const float* W2    = (const float*)d_in[25];
  const float* b2v   = (const float*)d_in[26];

  const int N    = in_sizes[0] / D;   // 50000
  const int E    = in_sizes[1] / 2;   // 400000
  const int Bb   = 8;
  const int MAXN = N / Bb;            // 6250

  const int* srcI = ei;
  const int* dstI = ei + E;

  size_t NF = (size_t)N;
  size_t ND = NF * D;
  float* fw = (float*)d_ws;
  short* qkvb = (short*)fw;              // N x 512 bf16 (q|k|v|xr); later kv16 aliases
  short* kv16 = qkvb;                    // N x 256 bf16
  float* ff2o = fw + NF * 256;           // N x 128 f32
  float* x1   = fw + NF * 384;           // N x 128 f32
  short* x1b  = (short*)(fw + NF * 512); // N x 128 bf16
  float* misc = fw + NF * 576;
  float* Qg    = misc;                // 64*128
  float* Og    = Qg + 8192;
  float* gout  = Og + 8192;
  float* Kg    = gout + 8192;
  float* Vg    = Kg + 8192;
  float* m_gl  = Vg + 8192;           // 512
  float* is_gl = m_gl + 512;          // 512
  float* Pbuf  = is_gl + 512;         // 8*4*MAXN
  float* offb  = Pbuf + (size_t)Bb * 4 * MAXN;   // 8 (+pad)
  float* bias512 = offb + 16;         // 512
  float* Plog  = bias512 + 512;       // 4*8*8*MAXN floats
  float* pm    = Plog + (size_t)4 * H * Bb * MAXN;
  float* ps    = pm + 512 * NCH;
  float* pacc  = ps + 512 * NCH;      // 512*NCH*16
  int* deg       = (int*)(pacc + 512 * NCH * 16);
  int* row_start = deg + N;           // N+1
  int* cursor    = row_start + N + 1;
  int* bsum      = cursor + N;        // <=1024
  int* edge_src  = bsum + 1024;       // E
  short* wbase = (short*)((((uintptr_t)(edge_src + E)) + 15) & ~(uintptr_t)15);
  short* cWq  = wbase;            // 4 x 128x128 stacked -> 512x128
  short* cWk  = cWq  + 16384;
  short* cWv  = cWk  + 16384;
  short* cWsk = cWv  + 16384;
  short* cNgK = cWsk + 16384;     // 2 x 128x128 stacked -> 256x128
  short* cNgV = cNgK + 16384;
  short* cGnQ = cNgV + 16384;
  short* cGnO = cGnQ + 16384;
  short* cW1  = cGnO + 16384;     // 256x128
  short* cW2  = cW1  + 32768;     // 128x256
  short* xb   = cW2  + 32768;     // N x 128 bf16 (x converted)

  float* outx   = (float*)d_out;
  float* outgh  = outx + ND;                       // 8192
  float* outreg = outgh + (size_t)Bb * NGT * D;    // 1
  float* wa     = outx;   // scratch fp32 N x 128

  const int GXM = (N + 127) / 128;    // 391
  const int SB  = (N + 1023) / 1024;  // 49
  dim3 blk256(256);

  // one-shot weight conversion + bias concat + x conversion
  CvtArgs ca;
  ca.s[0] = Wq;   ca.d[0] = cWq;  ca.n[0] = 16384;
  ca.s[1] = Wk;   ca.d[1] = cWk;  ca.n[1] = 16384;
  ca.s[2] = Wv;   ca.d[2] = cWv;  ca.n[2] = 16384;
  ca.s[3] = Wsk;  ca.d[3] = cWsk; ca.n[3] = 16384;
  ca.s[4] = ngw + 128 * 128; ca.d[4] = cNgK; ca.n[4] = 16384;
  ca.s[5] = ngw + 256 * 128; ca.d[5] = cNgV; ca.n[5] = 16384;
  ca.s[6] = gnw;  ca.d[6] = cGnQ; ca.n[6] = 16384;
  ca.s[7] = gnow; ca.d[7] = cGnO; ca.n[7] = 16384;
  ca.s[8] = W1;   ca.d[8] = cW1;  ca.n[8] = 32768;
  ca.s[9] = W2;   ca.d[9] = cW2;  ca.n[9] = 32768;
  cvt_weights<<<dim3(32, 10), blk256, 0, stream>>>(ca);
  concat_bias4<<<dim3(1), dim3(128), 0, stream>>>(bqv, bkv, bvv, bsk, bias512);
  cvt_x<<<dim3((N * 128 / 8 + 255) / 256), blk256, 0, stream>>>(x, xb, N * 128);

  // CSR build
  hipMemsetAsync(deg, 0, (size_t)N * sizeof(int), stream);
  count_deg<<<dim3((E + 255) / 256), blk256, 0, stream>>>(dstI, deg, E);
  scan_pass1<<<dim3(SB), blk256, 0, stream>>>(deg, bsum, N);
  scan_pass2<<<dim3(1), dim3(1024), 0, stream>>>(bsum, SB);
  scan_pass3<<<dim3(SB), blk256, 0, stream>>>(deg, bsum, row_start, cursor, N, E);
  fill_edges<<<dim3((E + 255) / 256), blk256, 0, stream>>>(dstI, srcI, cursor, edge_src, E);

  // fused tconv projections: all 512 cols -> qkvb bf16 (q|k|v|xr)
  gemm_direct<128><<<dim3(GXM, 4), blk256, 0, stream>>>(xb, cWq, bias512,
                                                        qkvb, 512, 512, nullptr, 0,
                                                        N, 512, 0);

  // edge attention + gate + LN  -> x1 (fp32) + x1b (bf16)
  tconv_attn<<<dim3((N * H + 255) / 256), blk256, 0, stream>>>(qkvb, row_start, edge_src, wa, N);
  gate_ln<<<dim3((N + 3) / 4), blk256, 0, stream>>>(x, wa, qkvb, Wbeta, x1, x1b, N);

  // global MHA: fused K|V projection (N x 256, bf16 out; aliases qkvb which is now dead)
  gemm_direct<128><<<dim3(GXM, 2), blk256, 0, stream>>>(x1b, cNgK, ngb + 128,
                                                        kv16, 256, 256, nullptr, 0,
                                                        N, 256, 0);
  gemm_small<<<dim3(64), dim3(128), 0, stream>>>(gh, ngw, ngb, Qg, 64);
  glob_part<<<dim3(512, NCH), dim3(64), 0, stream>>>(Qg, kv16, Plog, pm, ps, pacc, MAXN);
  glob_merge<<<dim3(512), dim3(64), 0, stream>>>(pm, ps, pacc, Og, m_gl, is_gl);
  pker2<<<dim3((MAXN + 255) / 256, 8), blk256, 0, stream>>>(Plog, m_gl, is_gl, Pbuf, MAXN);
  regk<<<dim3(8), blk256, 0, stream>>>(Pbuf, offb, MAXN);
  regfin<<<dim3(1), dim3(64), 0, stream>>>(offb, outreg);

  gemm_small<<<dim3(64), dim3(128), 0, stream>>>(Og, ngow, ngob, gout, 64);
  ln_add<<<dim3(16), blk256, 0, stream>>>(gh, gout, outgh, nullptr, 64);   // new global_h

  // nodes attend to global tokens: fused Qn-proj -> attention -> out-proj
  gemm_small<<<dim3(64), dim3(128), 0, stream>>>(outgh, gnw + 128 * 128, gnb + 128, Kg, 64);
  gemm_small<<<dim3(64), dim3(128), 0, stream>>>(outgh, gnw + 256 * 128, gnb + 256, Vg, 64);
  gemm_node<<<dim3(GXM), blk256, 0, stream>>>(x1b, cGnQ, gnb, Kg, Vg, cGnO, gnob,
                                              wa, N, MAXN);
  ln_add<<<dim3((N + 3) / 4), blk256, 0, stream>>>(x1, wa, x1, x1b, N);   // x2 fp32 + bf16

  // fused FF + final LN -> d_out x
  gemm_ff<<<dim3(GXM), blk256, 0, stream>>>(x1b, cW1, b1v, cW2, b2v, ff2o, N);
  ln_add<<<dim3((N + 3) / 4), blk256, 0, stream>>>(x1, ff2o, outx, nullptr, N);
}

// Round 14
// 359.968 us; speedup vs baseline: 1.0718x; 1.0005x over previous
//
#include <hip/hip_runtime.h>
#include <math.h>

#define D 128
#define H 8
#define NGT 8
#define LSTOK 4   // n_global_tokens_global (fixed by problem)
#define NCH 4     // node chunks for glob_part

typedef short bf16x8 __attribute__((ext_vector_type(8)));
typedef float f32x4  __attribute__((ext_vector_type(4)));

__device__ __forceinline__ short f2bf(float f) {
  union { float f; unsigned u; } v; v.f = f;
  unsigned r = v.u + 0x7FFFu + ((v.u >> 16) & 1u);   // RNE
  return (short)(r >> 16);
}
__device__ __forceinline__ float bf2f(short s) {
  union { unsigned u; float f; } v;
  v.u = ((unsigned)(unsigned short)s) << 16;
  return v.f;
}
__device__ __forceinline__ float4 bf4(bf16x8 v, int lo) {
  return make_float4(bf2f(v[lo]), bf2f(v[lo + 1]), bf2f(v[lo + 2]), bf2f(v[lo + 3]));
}
__device__ __forceinline__ unsigned pk2(float a, float b) {
  return ((unsigned)(unsigned short)f2bf(b) << 16) | (unsigned short)f2bf(a);
}

__device__ __forceinline__ float dot4(float4 a, float4 b) {
  return a.x*b.x + a.y*b.y + a.z*b.z + a.w*b.w;
}
__device__ __forceinline__ float4 scale_madd(float4 a, float sc, float4 v, float p) {
  return make_float4(fmaf(p, v.x, a.x*sc), fmaf(p, v.y, a.y*sc),
                     fmaf(p, v.z, a.z*sc), fmaf(p, v.w, a.w*sc));
}
__device__ __forceinline__ float4 comb4(float4 a, float e1, float4 c, float e2) {
  return make_float4(a.x*e1 + c.x*e2, a.y*e1 + c.y*e2, a.z*e1 + c.z*e2, a.w*e1 + c.w*e2);
}
__device__ __forceinline__ float4 shfl_xor4(float4 v, int off) {
  return make_float4(__shfl_xor(v.x, off), __shfl_xor(v.y, off),
                     __shfl_xor(v.z, off), __shfl_xor(v.w, off));
}

// ---------------- weight fp32 -> bf16 conversion (one-shot, 10 matrices) ----------------
struct CvtArgs {
  const float* s[10];
  short*       d[10];
  int          n[10];
};

__global__ void cvt_weights(CvtArgs a) {
  int which = blockIdx.y;
  const float* s = a.s[which];
  short* d = a.d[which];
  int n = a.n[which];
  int i = (blockIdx.x * 256 + threadIdx.x) * 4;
  if (i + 3 < n) {
    float4 v = *(const float4*)(s + i);
    d[i]     = f2bf(v.x);
    d[i + 1] = f2bf(v.y);
    d[i + 2] = f2bf(v.z);
    d[i + 3] = f2bf(v.w);
  }
}

// x fp32 -> bf16 (n divisible by 8)
__global__ void cvt_x(const float* __restrict__ s, short* __restrict__ d, int n) {
  int i = (blockIdx.x * 256 + threadIdx.x) * 8;
  if (i + 7 < n) {
    float4 a = *(const float4*)(s + i);
    float4 b = *(const float4*)(s + i + 4);
    bf16x8 v;
    v[0] = f2bf(a.x); v[1] = f2bf(a.y); v[2] = f2bf(a.z); v[3] = f2bf(a.w);
    v[4] = f2bf(b.x); v[5] = f2bf(b.y); v[6] = f2bf(b.z); v[7] = f2bf(b.w);
    *(bf16x8*)(d + i) = v;
  }
}

__global__ void concat_bias4(const float* __restrict__ b0, const float* __restrict__ b1,
                             const float* __restrict__ b2, const float* __restrict__ b3,
                             float* __restrict__ out) {
  int t = threadIdx.x;
  out[t] = b0[t]; out[128 + t] = b1[t]; out[256 + t] = b2[t]; out[384 + t] = b3[t];
}

// ---------------- direct MFMA GEMM (no staging LDS; LDS only for bf16 epilogue) -------
#define EPST 72   // LDS epilogue row stride in shorts (144B, 16B-aligned)
template<int K>
__global__ void __launch_bounds__(256) gemm_direct(const short* __restrict__ A,
    const short* __restrict__ Wb, const float* __restrict__ bias,
    short* __restrict__ out16, int C16, int s16,
    float* __restrict__ out32, int s32,
    int Nrows, int Ccols, int relu)
{
  __shared__ short eplds[4][64 * EPST];
  const int t = threadIdx.x;
  const int wid = t >> 6, lane = t & 63;
  const int rowBase = blockIdx.x * 128 + (wid >> 1) * 64;
  const int colBase = blockIdx.y * 128 + (wid & 1) * 64;
  const int lrow = lane & 15;
  const int lk = (lane >> 4) * 8;

  f32x4 acc[4][4];
  f32x4 z4 = {0.f, 0.f, 0.f, 0.f};
#pragma unroll
  for (int m = 0; m < 4; m++)
#pragma unroll
    for (int n = 0; n < 4; n++) acc[m][n] = z4;

  const short* ap[4];
#pragma unroll
  for (int m = 0; m < 4; ++m) {
    int ar = rowBase + m * 16 + lrow;
    if (ar >= Nrows) ar = Nrows - 1;
    ap[m] = A + (size_t)ar * K + lk;
  }
  const short* wp[4];
#pragma unroll
  for (int n = 0; n < 4; ++n)
    wp[n] = Wb + (size_t)(colBase + n * 16 + lrow) * K + lk;

#pragma unroll
  for (int kb = 0; kb < K; kb += 32) {
    bf16x8 af[4], bfr[4];
#pragma unroll
    for (int m = 0; m < 4; ++m) af[m] = *(const bf16x8*)(ap[m] + kb);
#pragma unroll
    for (int n = 0; n < 4; ++n) bfr[n] = *(const bf16x8*)(wp[n] + kb);
#pragma unroll
    for (int m = 0; m < 4; ++m)
#pragma unroll
      for (int n = 0; n < 4; ++n)
        acc[m][n] = __builtin_amdgcn_mfma_f32_16x16x32_bf16(af[m], bfr[n], acc[m][n], 0, 0, 0);
  }

  const int ccol = lane & 15;
  const int rquad = (lane >> 4) * 4;
  if (colBase < C16) {
    short* lds = eplds[wid];
#pragma unroll
    for (int n = 0; n < 4; ++n) {
      float bb = bias[colBase + n * 16 + ccol];
      int col = n * 16 + ccol;
#pragma unroll
      for (int m = 0; m < 4; ++m) {
        int r0 = m * 16 + rquad;
#pragma unroll
        for (int r = 0; r < 4; ++r) {
          float v = acc[m][n][r] + bb;
          if (relu) v = fmaxf(v, 0.f);
          lds[(r0 + r) * EPST + col] = f2bf(v);
        }
      }
    }
    const int jr = lane >> 3, jc = lane & 7;
#pragma unroll
    for (int i = 0; i < 8; ++i) {
      int row = i * 8 + jr;
      int gr = rowBase + row;
      if (gr < Nrows) {
        bf16x8 v = *(const bf16x8*)(lds + row * EPST + jc * 8);
        *(bf16x8*)(out16 + (size_t)gr * s16 + colBase + jc * 8) = v;
      }
    }
  } else {
#pragma unroll
    for (int n = 0; n < 4; ++n) {
      int col = colBase + n * 16 + ccol;
      float bb = bias[col];
#pragma unroll
      for (int m = 0; m < 4; ++m) {
        int row0 = rowBase + m * 16 + rquad;
#pragma unroll
        for (int r = 0; r < 4; ++r) {
          int gr = row0 + r;
          if (gr < Nrows) {
            float v = acc[m][n][r] + bb;
            if (relu) v = fmaxf(v, 0.f);
            out32[(size_t)gr * s32 + (col - C16)] = v;
          }
        }
      }
    }
  }
}

// ---------------- fused FF: out = relu(A@W1^T+b1)@W2^T+b2 (ff1 via LDS) ----------------
#define FFST 264   // LDS row stride in shorts for the 256-wide ff1 tile
__global__ void __launch_bounds__(256) gemm_ff(const short* __restrict__ A,
    const short* __restrict__ W1b, const float* __restrict__ b1,
    const short* __restrict__ W2b, const float* __restrict__ b2,
    float* __restrict__ out, int Nrows)
{
  __shared__ short flds[128 * FFST];
  const int t = threadIdx.x;
  const int wid = t >> 6, lane = t & 63;
  const int rowL = (wid >> 1) * 64;
  const int rowBase = blockIdx.x * 128 + rowL;
  const int lrow = lane & 15;
  const int lk = (lane >> 4) * 8;
  const int ccol = lane & 15;
  const int rquad = (lane >> 4) * 4;
  f32x4 z4 = {0.f, 0.f, 0.f, 0.f};

  const short* ap[4];
#pragma unroll
  for (int m = 0; m < 4; ++m) {
    int ar = rowBase + m * 16 + lrow;
    if (ar >= Nrows) ar = Nrows - 1;
    ap[m] = A + (size_t)ar * 128 + lk;
  }

  // ---- stage A: ff1 tile (128x256) in two 128-col passes -> LDS bf16 (relu'd) ----
  for (int cb = 0; cb < 2; ++cb) {
    int colBase = cb * 128 + (wid & 1) * 64;
    f32x4 acc[4][4];
#pragma unroll
    for (int m = 0; m < 4; m++)
#pragma unroll
      for (int n = 0; n < 4; n++) acc[m][n] = z4;
    const short* wp[4];
#pragma unroll
    for (int n = 0; n < 4; ++n)
      wp[n] = W1b + (size_t)(colBase + n * 16 + lrow) * 128 + lk;
#pragma unroll
    for (int kb = 0; kb < 128; kb += 32) {
      bf16x8 af[4], bfr[4];
#pragma unroll
      for (int m = 0; m < 4; ++m) af[m] = *(const bf16x8*)(ap[m] + kb);
#pragma unroll
      for (int n = 0; n < 4; ++n) bfr[n] = *(const bf16x8*)(wp[n] + kb);
#pragma unroll
      for (int m = 0; m < 4; ++m)
#pragma unroll
        for (int n = 0; n < 4; ++n)
          acc[m][n] = __builtin_amdgcn_mfma_f32_16x16x32_bf16(af[m], bfr[n], acc[m][n], 0, 0, 0);
    }
#pragma unroll
    for (int n = 0; n < 4; ++n) {
      int col = colBase + n * 16 + ccol;
      float bb = b1[col];
#pragma unroll
      for (int m = 0; m < 4; ++m) {
        int r0 = rowL + m * 16 + rquad;
#pragma unroll
        for (int r = 0; r < 4; ++r) {
          float v = fmaxf(acc[m][n][r] + bb, 0.f);
          flds[(r0 + r) * FFST + col] = f2bf(v);
        }
      }
    }
  }
  __syncthreads();

  // ---- stage B: out(128x128) = ff1 @ W2^T + b2, K=256, A from LDS ----
  {
    int colBase = (wid & 1) * 64;
    f32x4 acc[4][4];
#pragma unroll
    for (int m = 0; m < 4; m++)
#pragma unroll
      for (int n = 0; n < 4; n++) acc[m][n] = z4;
    const short* wp[4];
#pragma unroll
    for (int n = 0; n < 4; ++n)
      wp[n] = W2b + (size_t)(colBase + n * 16 + lrow) * 256 + lk;
#pragma unroll
    for (int kb = 0; kb < 256; kb += 32) {
      bf16x8 af[4], bfr[4];
#pragma unroll
      for (int m = 0; m < 4; ++m)
        af[m] = *(const bf16x8*)(flds + (rowL + m * 16 + lrow) * FFST + kb + lk);
#pragma unroll
      for (int n = 0; n < 4; ++n) bfr[n] = *(const bf16x8*)(wp[n] + kb);
#pragma unroll
      for (int m = 0; m < 4; ++m)
#pragma unroll
        for (int n = 0; n < 4; ++n)
          acc[m][n] = __builtin_amdgcn_mfma_f32_16x16x32_bf16(af[m], bfr[n], acc[m][n], 0, 0, 0);
    }
#pragma unroll
    for (int n = 0; n < 4; ++n) {
      int col = colBase + n * 16 + ccol;
      float bb = b2[col];
#pragma unroll
      for (int m = 0; m < 4; ++m) {
        int row0 = rowBase + m * 16 + rquad;
#pragma unroll
        for (int r = 0; r < 4; ++r) {
          int gr = row0 + r;
          if (gr < Nrows) out[(size_t)gr * 128 + col] = acc[m][n][r] + bb;
        }
      }
    }
  }
}

// ------- fused node path: Q=A@GnQ^T+b -> 8-token attention -> On@GnO^T+b -> out -------
// kg/vg in h-major layout (stride 132 floats): bank = (4h + c) % 32 -> conflict-free.
#define QST 136
#define KVST 132
__global__ void __launch_bounds__(256) gemm_node(const short* __restrict__ A,
    const short* __restrict__ GnQb, const float* __restrict__ gnbq,
    const float* __restrict__ Kg, const float* __restrict__ Vg,
    const short* __restrict__ GnOb, const float* __restrict__ gnbo,
    float* __restrict__ out, int Nrows, int MAXN)
{
  __shared__ short qlds[128 * QST];
  __shared__ float kg[2][NGT * KVST];
  __shared__ float vg[2][NGT * KVST];
  const int t = threadIdx.x;
  const int wid = t >> 6, lane = t & 63;
  const int rowL = (wid >> 1) * 64;
  const int n0 = blockIdx.x * 128;
  const int rowBase = n0 + rowL;
  const int colBase = (wid & 1) * 64;
  const int lrow = lane & 15;
  const int lk = (lane >> 4) * 8;
  const int ccol = lane & 15;
  const int rquad = (lane >> 4) * 4;
  f32x4 z4 = {0.f, 0.f, 0.f, 0.f};

  // stage K/V for the (up to 2) batches this block touches; transpose to h-major
  int b0 = n0 / MAXN;
  int nlast = n0 + 127; if (nlast >= Nrows) nlast = Nrows - 1;
  int bLast = nlast / MAXN;
  int nb = (bLast != b0) ? 2 : 1;
  for (int bi = 0; bi < nb; ++bi) {
    size_t gb = (size_t)((b0 + bi) * NGT) * 128;
    int i = t * 4;                 // 256 thr x 4 floats = 1024 = 8 tokens x 128
    int tk = i >> 7, d = i & 127;
    int li = (d >> 4) * KVST + tk * 16 + (d & 15);
    *(float4*)&kg[bi][li] = *(const float4*)(Kg + gb + i);
    *(float4*)&vg[bi][li] = *(const float4*)(Vg + gb + i);
  }

  // ---- stage A: Q tile = A @ GnQ^T + bias -> qlds bf16 ----
  {
    f32x4 acc[4][4];
#pragma unroll
    for (int m = 0; m < 4; m++)
#pragma unroll
      for (int n = 0; n < 4; n++) acc[m][n] = z4;
    const short* ap[4];
#pragma unroll
    for (int m = 0; m < 4; ++m) {
      int ar = rowBase + m * 16 + lrow;
      if (ar >= Nrows) ar = Nrows - 1;
      ap[m] = A + (size_t)ar * 128 + lk;
    }
    const short* wp[4];
#pragma unroll
    for (int n = 0; n < 4; ++n)
      wp[n] = GnQb + (size_t)(colBase + n * 16 + lrow) * 128 + lk;
#pragma unroll
    for (int kb = 0; kb < 128; kb += 32) {
      bf16x8 af[4], bfr[4];
#pragma unroll
      for (int m = 0; m < 4; ++m) af[m] = *(const bf16x8*)(ap[m] + kb);
#pragma unroll
      for (int n = 0; n < 4; ++n) bfr[n] = *(const bf16x8*)(wp[n] + kb);
#pragma unroll
      for (int m = 0; m < 4; ++m)
#pragma unroll
        for (int n = 0; n < 4; ++n)
          acc[m][n] = __builtin_amdgcn_mfma_f32_16x16x32_bf16(af[m], bfr[n], acc[m][n], 0, 0, 0);
    }
#pragma unroll
    for (int n = 0; n < 4; ++n) {
      int col = colBase + n * 16 + ccol;
      float bb = gnbq[col];
#pragma unroll
      for (int m = 0; m < 4; ++m) {
        int r0 = rowL + m * 16 + rquad;
#pragma unroll
        for (int r = 0; r < 4; ++r)
          qlds[(r0 + r) * QST + col] = f2bf(acc[m][n][r] + bb);
      }
    }
  }
  __syncthreads();

  // ---- stage B: per-(row,h) attention over 8 tokens; On overwrites Q slot ----
#pragma unroll
  for (int u = 0; u < 4; ++u) {
    int unit = t + u * 256;            // 0..1023
    int row = unit >> 3, h = unit & 7;
    int grow = n0 + row;
    if (grow < Nrows) {
      int bi = (grow / MAXN) - b0;
      short* qp = qlds + row * QST + h * 16;
      bf16x8 qa = *(const bf16x8*)(qp);
      bf16x8 qb = *(const bf16x8*)(qp + 8);
      float4 q0 = bf4(qa, 0), q1 = bf4(qa, 4), q2 = bf4(qb, 0), q3 = bf4(qb, 4);
      const float* kh = &kg[bi][h * KVST];
      const float* vh = &vg[bi][h * KVST];
      float l[NGT];
      float mx = -3.0e38f;
#pragma unroll
      for (int tk = 0; tk < NGT; tk++) {
        const float4* k4 = (const float4*)(kh + tk * 16);
        float d = dot4(q0, k4[0]) + dot4(q1, k4[1]) + dot4(q2, k4[2]) + dot4(q3, k4[3]);
        l[tk] = d * 0.25f;
        mx = fmaxf(mx, l[tk]);
      }
      float s = 0.f;
#pragma unroll
      for (int tk = 0; tk < NGT; tk++) { l[tk] = expf(l[tk] - mx); s += l[tk]; }
      float inv = 1.f / s;
      float4 a0 = make_float4(0, 0, 0, 0), a1 = a0, a2 = a0, a3 = a0;
#pragma unroll
      for (int tk = 0; tk < NGT; tk++) {
        float p = l[tk] * inv;
        const float4* v4 = (const float4*)(vh + tk * 16);
        a0 = scale_madd(a0, 1.f, v4[0], p);
        a1 = scale_madd(a1, 1.f, v4[1], p);
        a2 = scale_madd(a2, 1.f, v4[2], p);
        a3 = scale_madd(a3, 1.f, v4[3], p);
      }
      unsigned* o = (unsigned*)qp;
      o[0] = pk2(a0.x, a0.y); o[1] = pk2(a0.z, a0.w);
      o[2] = pk2(a1.x, a1.y); o[3] = pk2(a1.z, a1.w);
      o[4] = pk2(a2.x, a2.y); o[5] = pk2(a2.z, a2.w);
      o[6] = pk2(a3.x, a3.y); o[7] = pk2(a3.z, a3.w);
    }
  }
  __syncthreads();

  // ---- stage C: out = On @ GnO^T + bias (fp32, coalesced) ----
  {
    f32x4 acc[4][4];
#pragma unroll
    for (int m = 0; m < 4; m++)
#pragma unroll
      for (int n = 0; n < 4; n++) acc[m][n] = z4;
    const short* wp[4];
#pragma unroll
    for (int n = 0; n < 4; ++n)
      wp[n] = GnOb + (size_t)(colBase + n * 16 + lrow) * 128 + lk;
#pragma unroll
    for (int kb = 0; kb < 128; kb += 32) {
      bf16x8 af[4], bfr[4];
#pragma unroll
      for (int m = 0; m < 4; ++m)
        af[m] = *(const bf16x8*)(qlds + (rowL + m * 16 + lrow) * QST + kb + lk);
#pragma unroll
      for (int n = 0; n < 4; ++n) bfr[n] = *(const bf16x8*)(wp[n] + kb);
#pragma unroll
      for (int m = 0; m < 4; ++m)
#pragma unroll
        for (int n = 0; n < 4; ++n)
          acc[m][n] = __builtin_amdgcn_mfma_f32_16x16x32_bf16(af[m], bfr[n], acc[m][n], 0, 0, 0);
    }
#pragma unroll
    for (int n = 0; n < 4; ++n) {
      int col = colBase + n * 16 + ccol;
      float bb = gnbo[col];
#pragma unroll
      for (int m = 0; m < 4; ++m) {
        int row0 = rowBase + m * 16 + rquad;
#pragma unroll
        for (int r = 0; r < 4; ++r) {
          int gr = row0 + r;
          if (gr < Nrows) out[(size_t)gr * 128 + col] = acc[m][n][r] + bb;
        }
      }
    }
  }
}

// small GEMM (M rows <= 64, K=C=128): one block per row
__global__ void gemm_small(const float* __restrict__ A, const float* __restrict__ W,
                           const float* __restrict__ bias, float* __restrict__ out, int M)
{
  int r = blockIdx.x;
  int c = threadIdx.x;
  __shared__ float as[128];
  as[c] = A[(size_t)r * 128 + c];
  __syncthreads();
  float acc = bias[c];
  const float* wr = W + (size_t)c * 128;
#pragma unroll 4
  for (int k = 0; k < 128; k++) acc += as[k] * wr[k];
  out[(size_t)r * 128 + c] = acc;
}

// two small GEMMs in one launch (grid 128: blocks 0..63 -> {W0,b0,o0}, 64..127 -> {W1,b1,o1})
__global__ void gemm_small2(const float* __restrict__ A,
                            const float* __restrict__ W0, const float* __restrict__ b0, float* __restrict__ o0,
                            const float* __restrict__ W1, const float* __restrict__ b1, float* __restrict__ o1)
{
  int which = blockIdx.x >> 6;
  int r = blockIdx.x & 63;
  const float* W = which ? W1 : W0;
  const float* bias = which ? b1 : b0;
  float* out = which ? o1 : o0;
  int c = threadIdx.x;
  __shared__ float as[128];
  as[c] = A[(size_t)r * 128 + c];
  __syncthreads();
  float acc = bias[c];
  const float* wr = W + (size_t)c * 128;
#pragma unroll 4
  for (int k = 0; k < 128; k++) acc += as[k] * wr[k];
  out[(size_t)r * 128 + c] = acc;
}

// ---------------- CSR build ----------------
__global__ void count_deg(const int* __restrict__ dst, int* __restrict__ deg, int E) {
  int e = blockIdx.x * 256 + threadIdx.x;
  if (e < E) atomicAdd(&deg[dst[e]], 1);
}

__global__ void scan_pass1(const int* __restrict__ deg, int* __restrict__ bsum, int N) {
  int t = threadIdx.x, lane = t & 63, wid = t >> 6;
  int idx = blockIdx.x * 1024 + t * 4;
  int4 v = {0, 0, 0, 0};
  if (idx + 3 < N) v = *(const int4*)(deg + idx);
  else {
    if (idx < N) v.x = deg[idx];
    if (idx + 1 < N) v.y = deg[idx + 1];
    if (idx + 2 < N) v.z = deg[idx + 2];
    if (idx + 3 < N) v.w = deg[idx + 3];
  }
  int s = v.x + v.y + v.z + v.w;
#pragma unroll
  for (int off = 32; off >= 1; off >>= 1) s += __shfl_xor(s, off);
  __shared__ int ws[4];
  if (lane == 0) ws[wid] = s;
  __syncthreads();
  if (t == 0) bsum[blockIdx.x] = ws[0] + ws[1] + ws[2] + ws[3];
}

__global__ void scan_pass2(int* __restrict__ bsum, int SB) {
  __shared__ int sh[1024];
  int t = threadIdx.x;
  sh[t] = (t < SB) ? bsum[t] : 0;
  __syncthreads();
  for (int off = 1; off < 1024; off <<= 1) {
    int v = (t >= off) ? sh[t - off] : 0;
    __syncthreads();
    sh[t] += v;
    __syncthreads();
  }
  if (t < SB) bsum[t] = (t == 0) ? 0 : sh[t - 1];
}

__global__ void scan_pass3(const int* __restrict__ deg, const int* __restrict__ bsum,
                           int* __restrict__ row_start, int* __restrict__ cursor,
                           int N, int E)
{
  int t = threadIdx.x, lane = t & 63, wid = t >> 6;
  int idx = blockIdx.x * 1024 + t * 4;
  int4 v = {0, 0, 0, 0};
  if (idx + 3 < N) v = *(const int4*)(deg + idx);
  else {
    if (idx < N) v.x = deg[idx];
    if (idx + 1 < N) v.y = deg[idx + 1];
    if (idx + 2 < N) v.z = deg[idx + 2];
    if (idx + 3 < N) v.w = deg[idx + 3];
  }
  int ts = v.x + v.y + v.z + v.w;
  int x = ts;
#pragma unroll
  for (int off = 1; off < 64; off <<= 1) {
    int y = __shfl_up(x, off);
    if (lane >= off) x += y;
  }
  __shared__ int ws[4];
  if (lane == 63) ws[wid] = x;
  __syncthreads();
  int woff = 0;
  for (int i = 0; i < wid; i++) woff += ws[i];
  int p = bsum[blockIdx.x] + woff + (x - ts);
  if (idx < N)     { row_start[idx] = p; cursor[idx] = p; }     p += v.x;
  if (idx + 1 < N) { row_start[idx + 1] = p; cursor[idx + 1] = p; } p += v.y;
  if (idx + 2 < N) { row_start[idx + 2] = p; cursor[idx + 2] = p; } p += v.z;
  if (idx + 3 < N) { row_start[idx + 3] = p; cursor[idx + 3] = p; }
  if (blockIdx.x == 0 && t == 0) row_start[N] = E;
}

__global__ void fill_edges(const int* __restrict__ dst, const int* __restrict__ src,
                           int* __restrict__ cursor, int* __restrict__ edge_src, int E) {
  int e = blockIdx.x * 256 + threadIdx.x;
  if (e < E) {
    int p = atomicAdd(&cursor[dst[e]], 1);
    edge_src[p] = src[e];
  }
}

// ---------------- tconv edge attention: q|k|v|xr bf16 (qkvb stride 512) ----------------
__global__ void tconv_attn(const short* __restrict__ qkvb,
                           const int* __restrict__ row_start,
                           const int* __restrict__ edge_src,
                           float* __restrict__ out, int N)
{
  int gid = blockIdx.x * 256 + threadIdx.x;
  if (gid >= N * H) return;
  int n = gid >> 3, h = gid & 7;
  const short* qp = qkvb + (size_t)n * 512 + h * 16;
  bf16x8 qa = *(const bf16x8*)(qp);
  bf16x8 qb = *(const bf16x8*)(qp + 8);
  float4 q0 = bf4(qa, 0), q1 = bf4(qa, 4), q2 = bf4(qb, 0), q3 = bf4(qb, 4);
  int e0 = row_start[n], e1 = row_start[n + 1];

  float mA = -3.0e38f, sA = 0.f;
  float4 A0 = make_float4(0, 0, 0, 0), A1 = A0, A2 = A0, A3 = A0;
  float mB = -3.0e38f, sB = 0.f;
  float4 B0 = A0, B1 = A0, B2 = A0, B3 = A0;

  int ei = e0;
  for (; ei + 1 < e1; ei += 2) {
    int sn0 = edge_src[ei], sn1 = edge_src[ei + 1];
    const short* kp0 = qkvb + (size_t)sn0 * 512 + 128 + h * 16;
    const short* kp1 = qkvb + (size_t)sn1 * 512 + 128 + h * 16;
    bf16x8 k00 = *(const bf16x8*)(kp0);
    bf16x8 k01 = *(const bf16x8*)(kp0 + 8);
    bf16x8 k10 = *(const bf16x8*)(kp1);
    bf16x8 k11 = *(const bf16x8*)(kp1 + 8);
    float d0 = (dot4(q0, bf4(k00, 0)) + dot4(q1, bf4(k00, 4))
              + dot4(q2, bf4(k01, 0)) + dot4(q3, bf4(k01, 4))) * 0.25f;
    float d1 = (dot4(q0, bf4(k10, 0)) + dot4(q1, bf4(k10, 4))
              + dot4(q2, bf4(k11, 0)) + dot4(q3, bf4(k11, 4))) * 0.25f;
    bf16x8 v00 = *(const bf16x8*)(kp0 + 128);
    bf16x8 v01 = *(const bf16x8*)(kp0 + 136);
    bf16x8 v10 = *(const bf16x8*)(kp1 + 128);
    bf16x8 v11 = *(const bf16x8*)(kp1 + 136);
    float mn0 = fmaxf(mA, d0);
    float sc0 = expf(mA - mn0), p0 = expf(d0 - mn0);
    A0 = scale_madd(A0, sc0, bf4(v00, 0), p0);
    A1 = scale_madd(A1, sc0, bf4(v00, 4), p0);
    A2 = scale_madd(A2, sc0, bf4(v01, 0), p0);
    A3 = scale_madd(A3, sc0, bf4(v01, 4), p0);
    sA = sA * sc0 + p0; mA = mn0;
    float mn1 = fmaxf(mB, d1);
    float sc1 = expf(mB - mn1), p1 = expf(d1 - mn1);
    B0 = scale_madd(B0, sc1, bf4(v10, 0), p1);
    B1 = scale_madd(B1, sc1, bf4(v10, 4), p1);
    B2 = scale_madd(B2, sc1, bf4(v11, 0), p1);
    B3 = scale_madd(B3, sc1, bf4(v11, 4), p1);
    sB = sB * sc1 + p1; mB = mn1;
  }
  if (ei < e1) {
    int sn0 = edge_src[ei];
    const short* kp0 = qkvb + (size_t)sn0 * 512 + 128 + h * 16;
    bf16x8 k00 = *(const bf16x8*)(kp0);
    bf16x8 k01 = *(const bf16x8*)(kp0 + 8);
    float d0 = (dot4(q0, bf4(k00, 0)) + dot4(q1, bf4(k00, 4))
              + dot4(q2, bf4(k01, 0)) + dot4(q3, bf4(k01, 4))) * 0.25f;
    bf16x8 v00 = *(const bf16x8*)(kp0 + 128);
    bf16x8 v01 = *(const bf16x8*)(kp0 + 136);
    float mn0 = fmaxf(mA, d0);
    float sc0 = expf(mA - mn0), p0 = expf(d0 - mn0);
    A0 = scale_madd(A0, sc0, bf4(v00, 0), p0);
    A1 = scale_madd(A1, sc0, bf4(v00, 4), p0);
    A2 = scale_madd(A2, sc0, bf4(v01, 0), p0);
    A3 = scale_madd(A3, sc0, bf4(v01, 4), p0);
    sA = sA * sc0 + p0; mA = mn0;
  }
  float mn = fmaxf(mA, mB);
  float eA = expf(mA - mn), eB = expf(mB - mn);
  float s = sA * eA + sB * eB;
  float4 a0 = comb4(A0, eA, B0, eB);
  float4 a1 = comb4(A1, eA, B1, eB);
  float4 a2 = comb4(A2, eA, B2, eB);
  float4 a3 = comb4(A3, eA, B3, eB);
  float inv = 1.f / (s + 1e-16f);
  float4* o4 = (float4*)(out + (size_t)n * 128 + h * 16);
  o4[0] = make_float4(a0.x * inv, a0.y * inv, a0.z * inv, a0.w * inv);
  o4[1] = make_float4(a1.x * inv, a1.y * inv, a1.z * inv, a1.w * inv);
  o4[2] = make_float4(a2.x * inv, a2.y * inv, a2.z * inv, a2.w * inv);
  o4[3] = make_float4(a3.x * inv, a3.y * inv, a3.z * inv, a3.w * inv);
}

// ---------------- gate + residual + LN -> x1 (fp32) + x1b (bf16); xr bf16 in qkvb ------
__global__ void gate_ln(const float* __restrict__ x, const float* __restrict__ att,
                        const short* __restrict__ qkvb, const float* __restrict__ Wb,
                        float* __restrict__ x1, short* __restrict__ x1b, int N)
{
  int wid = threadIdx.x >> 6, lane = threadIdx.x & 63;
  int n = blockIdx.x * 4 + wid;
  if (n >= N) return;
  size_t base = (size_t)n * 128 + lane * 2;
  float2 o = *(const float2*)(att + base);
  unsigned ru = *(const unsigned*)(qkvb + (size_t)n * 512 + 384 + lane * 2);
  float2 r = make_float2(bf2f((short)(ru & 0xFFFF)), bf2f((short)(ru >> 16)));
  float2 xv = *(const float2*)(x + base);
  float2 w0 = *(const float2*)(Wb + lane * 2);
  float2 w1 = *(const float2*)(Wb + 128 + lane * 2);
  float2 w2 = *(const float2*)(Wb + 256 + lane * 2);
  float ts = o.x * w0.x + o.y * w0.y + r.x * w1.x + r.y * w1.y
           + (o.x - r.x) * w2.x + (o.y - r.y) * w2.y;
#pragma unroll
  for (int mm = 32; mm >= 1; mm >>= 1) ts += __shfl_xor(ts, mm);
  float beta = 1.f / (1.f + expf(-ts));
  float2 y;
  y.x = xv.x + beta * r.x + (1.f - beta) * o.x;
  y.y = xv.y + beta * r.y + (1.f - beta) * o.y;
  float sm = y.x + y.y;
#pragma unroll
  for (int mm = 32; mm >= 1; mm >>= 1) sm += __shfl_xor(sm, mm);
  float mean = sm * (1.f / 128.f);
  float dx = y.x - mean, dy = y.y - mean;
  float vs = dx * dx + dy * dy;
#pragma unroll
  for (int mm = 32; mm >= 1; mm >>= 1) vs += __shfl_xor(vs, mm);
  float rstd = rsqrtf(vs * (1.f / 128.f) + 1e-5f);
  float ox = dx * rstd, oy = dy * rstd;
  *(float2*)(x1 + base) = make_float2(ox, oy);
  *(unsigned*)(x1b + base) = pk2(ox, oy);
}

// ---------------- out = LN(a + b); optional bf16 copy ----------------
__global__ void ln_add(const float* __restrict__ a, const float* __restrict__ b,
                       float* __restrict__ out, short* __restrict__ out16, int R)
{
  int wid = threadIdx.x >> 6, lane = threadIdx.x & 63;
  int r = blockIdx.x * 4 + wid;
  if (r >= R) return;
  size_t base = (size_t)r * 128 + lane * 2;
  float2 av = *(const float2*)(a + base);
  float2 bv = *(const float2*)(b + base);
  float2 y = make_float2(av.x + bv.x, av.y + bv.y);
  float sm = y.x + y.y;
#pragma unroll
  for (int mm = 32; mm >= 1; mm >>= 1) sm += __shfl_xor(sm, mm);
  float mean = sm * (1.f / 128.f);
  float dx = y.x - mean, dy = y.y - mean;
  float vs = dx * dx + dy * dy;
#pragma unroll
  for (int mm = 32; mm >= 1; mm >>= 1) vs += __shfl_xor(vs, mm);
  float rstd = rsqrtf(vs * (1.f / 128.f) + 1e-5f);
  float ox = dx * rstd, oy = dy * rstd;
  *(float2*)(out + base) = make_float2(ox, oy);
  if (out16) *(unsigned*)(out16 + base) = pk2(ox, oy);
}

// ---------------- glob attention, pass 1: partial online softmax over node chunks ------
__global__ void glob_part(const float* __restrict__ Qg, const short* __restrict__ kv,
                          float* __restrict__ Plog,
                          float* __restrict__ pm, float* __restrict__ ps,
                          float* __restrict__ pacc, int MAXN)
{
  int blk = blockIdx.x;                 // b*64 + g*8 + h
  int ch = blockIdx.y;
  int h = blk & 7, g = (blk >> 3) & 7, b = blk >> 6;
  int lane = threadIdx.x;
  const float4* q4 = (const float4*)(Qg + (size_t)(b * NGT + g) * 128 + h * 16);
  float4 q0 = q4[0], q1 = q4[1], q2 = q4[2], q3 = q4[3];
  int chunk = (MAXN + NCH - 1) / NCH;
  int n0 = ch * chunk;
  int n1 = n0 + chunk; if (n1 > MAXN) n1 = MAXN;
  float* plrow = (g >= LSTOK) ? Plog + (((size_t)(b * 4 + g - LSTOK)) * H + h) * MAXN : nullptr;
  float m = -3.0e38f, s = 0.f;
  float4 a0 = make_float4(0, 0, 0, 0), a1 = a0, a2 = a0, a3 = a0;
  for (int n = n0 + lane; n < n1; n += 64) {
    const short* kp = kv + ((size_t)(b * MAXN + n)) * 256 + h * 16;
    bf16x8 k0 = *(const bf16x8*)(kp);
    bf16x8 k1 = *(const bf16x8*)(kp + 8);
    float d = dot4(q0, bf4(k0, 0)) + dot4(q1, bf4(k0, 4))
            + dot4(q2, bf4(k1, 0)) + dot4(q3, bf4(k1, 4));
    d *= 0.25f;
    if (plrow) plrow[n] = d;
    float mn = fmaxf(m, d);
    float sc = expf(m - mn);
    float p = expf(d - mn);
    bf16x8 v0 = *(const bf16x8*)(kp + 128);
    bf16x8 v1 = *(const bf16x8*)(kp + 136);
    a0 = scale_madd(a0, sc, bf4(v0, 0), p);
    a1 = scale_madd(a1, sc, bf4(v0, 4), p);
    a2 = scale_madd(a2, sc, bf4(v1, 0), p);
    a3 = scale_madd(a3, sc, bf4(v1, 4), p);
    s = s * sc + p;
    m = mn;
  }
#pragma unroll
  for (int off = 32; off >= 1; off >>= 1) {
    float m2 = __shfl_xor(m, off);
    float s2 = __shfl_xor(s, off);
    float4 c0 = shfl_xor4(a0, off), c1 = shfl_xor4(a1, off);
    float4 c2 = shfl_xor4(a2, off), c3 = shfl_xor4(a3, off);
    float mn = fmaxf(m, m2);
    float e1 = expf(m - mn), e2 = expf(m2 - mn);
    s = s * e1 + s2 * e2;
    a0 = comb4(a0, e1, c0, e2);
    a1 = comb4(a1, e1, c1, e2);
    a2 = comb4(a2, e1, c2, e2);
    a3 = comb4(a3, e1, c3, e2);
    m = mn;
  }
  if (lane == 0) {
    int pi = blk * NCH + ch;
    pm[pi] = m; ps[pi] = s;
    float4* pa = (float4*)(pacc + (size_t)pi * 16);
    pa[0] = a0; pa[1] = a1; pa[2] = a2; pa[3] = a3;
  }
}

__global__ void glob_merge(const float* __restrict__ pm, const float* __restrict__ ps,
                           const float* __restrict__ pacc, float* __restrict__ Og,
                           float* __restrict__ m_gl, float* __restrict__ is_gl)
{
  int blk = blockIdx.x;
  int lane = threadIdx.x;
  float m = -3.0e38f;
#pragma unroll
  for (int c = 0; c < NCH; ++c) m = fmaxf(m, pm[blk * NCH + c]);
  float s = 0.f;
#pragma unroll
  for (int c = 0; c < NCH; ++c) s += ps[blk * NCH + c] * expf(pm[blk * NCH + c] - m);
  if (lane < 16) {
    float a = 0.f;
#pragma unroll
    for (int c = 0; c < NCH; ++c)
      a += pacc[(size_t)(blk * NCH + c) * 16 + lane] * expf(pm[blk * NCH + c] - m);
    int h = blk & 7, g = (blk >> 3) & 7, b = blk >> 6;
    Og[(size_t)(b * NGT + g) * 128 + h * 16 + lane] = a / s;
  }
  if (lane == 0) { m_gl[blk] = m; is_gl[blk] = 1.f / s; }
}

// ---------------- P rows from stored logits ----------------
__global__ void pker2(const float* __restrict__ Plog,
                      const float* __restrict__ m_gl, const float* __restrict__ is_gl,
                      float* __restrict__ P, int MAXN)
{
  int b = blockIdx.y;
  __shared__ float ms[32], iss[32];
  if (threadIdx.x < 32) {
    int g = threadIdx.x >> 3, h = threadIdx.x & 7;
    ms[threadIdx.x]  = m_gl[(b * NGT + LSTOK + g) * H + h];
    iss[threadIdx.x] = is_gl[(b * NGT + LSTOK + g) * H + h];
  }
  __syncthreads();
  int n = blockIdx.x * 256 + threadIdx.x;
  if (n >= MAXN) return;
#pragma unroll
  for (int g = 0; g < 4; g++) {
    float acc = 0.f;
#pragma unroll
    for (int h = 0; h < H; h++) {
      float l = Plog[(((size_t)(b * 4 + g)) * H + h) * MAXN + n];
      acc += expf(l - ms[g * 8 + h]) * iss[g * 8 + h];
    }
    P[(size_t)(b * 4 + g) * MAXN + n] = acc * 0.125f;
  }
}

// ---------------- reg: off-diagonal Gram of row-normalized P ----------------
__global__ void regk(const float* __restrict__ P, float* __restrict__ offb, int MAXN)
{
  int b = blockIdx.x;
  int t = threadIdx.x;
  float v[10];
#pragma unroll
  for (int i = 0; i < 10; i++) v[i] = 0.f;
  for (int n = t; n < MAXN; n += 256) {
    float p0 = P[(size_t)(b * 4 + 0) * MAXN + n];
    float p1 = P[(size_t)(b * 4 + 1) * MAXN + n];
    float p2 = P[(size_t)(b * 4 + 2) * MAXN + n];
    float p3 = P[(size_t)(b * 4 + 3) * MAXN + n];
    v[0] += p0; v[1] += p1; v[2] += p2; v[3] += p3;
    v[4] += p0 * p1; v[5] += p0 * p2; v[6] += p0 * p3;
    v[7] += p1 * p2; v[8] += p1 * p3; v[9] += p2 * p3;
  }
#pragma unroll
  for (int i = 0; i < 10; i++) {
    float x = v[i];
#pragma unroll
    for (int mm = 32; mm >= 1; mm >>= 1) x += __shfl_xor(x, mm);
    v[i] = x;
  }
  __shared__ float red[4][10];
  int wid = t >> 6, lane = t & 63;
  if (lane == 0)
    for (int i = 0; i < 10; i++) red[wid][i] = v[i];
  __syncthreads();
  if (t == 0) {
    float r[10];
    for (int i = 0; i < 10; i++) r[i] = red[0][i] + red[1][i] + red[2][i] + red[3][i];
    float r0 = r[0] + 1e-8f, r1 = r[1] + 1e-8f, r2 = r[2] + 1e-8f, r3 = r[3] + 1e-8f;
    float off = 2.f * (r[4] / (r0 * r1) + r[5] / (r0 * r2) + r[6] / (r0 * r3)
                     + r[7] / (r1 * r2) + r[8] / (r1 * r3) + r[9] / (r2 * r3));
    offb[b] = off * (1.f / 12.f);   // (Kt*Kt - Kt) = 12
  }
}

__global__ void regfin(const float* __restrict__ offb, float* __restrict__ out) {
  if (threadIdx.x == 0 && blockIdx.x == 0) {
    float s = 0.f;
    for (int i = 0; i < 8; i++) s += offb[i];
    *out = s * (1.f / 8.f);
  }
}

extern "C" void kernel_launch(void* const* d_in, const int* in_sizes, int n_in,
                              void* d_out, int out_size, void* d_ws, size_t ws_size,
                              hipStream_t stream)
{
  const float* x     = (const float*)d_in[0];
  const int*   ei    = (const int*)d_in[1];
  const float* gh    = (const float*)d_in[2];
  const float* Wq    = (const float*)d_in[6];
  const float* bqv   = (const float*)d_in[7];
  const float* Wk    = (const float*)d_in[8];
  const float* bkv   = (const float*)d_in[9];
  const float* Wv    = (const float*)d_in[10];
  const float* bvv   = (const float*)d_in[11];
  const float* Wsk   = (const float*)d_in[12];
  const float* bsk   = (const float*)d_in[13];
  const float* Wbeta = (const float*)d_in[14];
  const float* ngw   = (const float*)d_in[15];
  const float* ngb   = (const float*)d_in[16];
  const float* ngow  = (const float*)d_in[17];
  const float* ngob  = (const float*)d_in[18];
  const float* gnw   = (const float*)d_in[19];
  const float* gnb   = (const float*)d_in[20];
  const float* gnow  = (const float*)d_in[21];
  const float* gnob  = (const float*)d_in[22];
  const float* W1    = (const float*)d_in[23];
  const float* b1v   = (const float*)d_in[24];
  const float* W2    = (const float*)d_in[25];
  const float* b2v   = (const float*)d_in[26];

  const int N    = in_sizes[0] / D;   // 50000
  const int E    = in_sizes[1] / 2;   // 400000
  const int Bb   = 8;
  const int MAXN = N / Bb;            // 6250

  const int* srcI = ei;
  const int* dstI = ei + E;

  size_t NF = (size_t)N;
  size_t ND = NF * D;
  float* fw = (float*)d_ws;
  short* qkvb = (short*)fw;              // N x 512 bf16 (q|k|v|xr); later kv16 aliases
  short* kv16 = qkvb;                    // N x 256 bf16
  float* ff2o = fw + NF * 256;           // N x 128 f32
  float* x1   = fw + NF * 384;           // N x 128 f32
  short* x1b  = (short*)(fw + NF * 512); // N x 128 bf16
  float* misc = fw + NF * 576;
  float* Qg    = misc;                // 64*128
  float* Og    = Qg + 8192;
  float* gout  = Og + 8192;
  float* Kg    = gout + 8192;
  float* Vg    = Kg + 8192;
  float* m_gl  = Vg + 8192;           // 512
  float* is_gl = m_gl + 512;          // 512
  float* Pbuf  = is_gl + 512;         // 8*4*MAXN
  float* offb  = Pbuf + (size_t)Bb * 4 * MAXN;   // 8 (+pad)
  float* bias512 = offb + 16;         // 512
  float* Plog  = bias512 + 512;       // 4*8*8*MAXN floats
  float* pm    = Plog + (size_t)4 * H * Bb * MAXN;
  float* ps    = pm + 512 * NCH;
  float* pacc  = ps + 512 * NCH;      // 512*NCH*16
  int* deg       = (int*)(pacc + 512 * NCH * 16);
  int* row_start = deg + N;           // N+1
  int* cursor    = row_start + N + 1;
  int* bsum      = cursor + N;        // <=1024
  int* edge_src  = bsum + 1024;       // E
  short* wbase = (short*)((((uintptr_t)(edge_src + E)) + 15) & ~(uintptr_t)15);
  short* cWq  = wbase;            // 4 x 128x128 stacked -> 512x128
  short* cWk  = cWq  + 16384;
  short* cWv  = cWk  + 16384;
  short* cWsk = cWv  + 16384;
  short* cNgK = cWsk + 16384;     // 2 x 128x128 stacked -> 256x128
  short* cNgV = cNgK + 16384;
  short* cGnQ = cNgV + 16384;
  short* cGnO = cGnQ + 16384;
  short* cW1  = cGnO + 16384;     // 256x128
  short* cW2  = cW1  + 32768;     // 128x256
  short* xb   = cW2  + 32768;     // N x 128 bf16 (x converted)

  float* outx   = (float*)d_out;
  float* outgh  = outx + ND;                       // 8192
  float* outreg = outgh + (size_t)Bb * NGT * D;    // 1
  float* wa     = outx;   // scratch fp32 N x 128

  const int GXM = (N + 127) / 128;    // 391
  const int SB  = (N + 1023) / 1024;  // 49
  dim3 blk256(256);

  // one-shot weight conversion + bias concat + x conversion
  CvtArgs ca;
  ca.s[0] = Wq;   ca.d[0] = cWq;  ca.n[0] = 16384;
  ca.s[1] = Wk;   ca.d[1] = cWk;  ca.n[1] = 16384;
  ca.s[2] = Wv;   ca.d[2] = cWv;  ca.n[2] = 16384;
  ca.s[3] = Wsk;  ca.d[3] = cWsk; ca.n[3] = 16384;
  ca.s[4] = ngw + 128 * 128; ca.d[4] = cNgK; ca.n[4] = 16384;
  ca.s[5] = ngw + 256 * 128; ca.d[5] = cNgV; ca.n[5] = 16384;
  ca.s[6] = gnw;  ca.d[6] = cGnQ; ca.n[6] = 16384;
  ca.s[7] = gnow; ca.d[7] = cGnO; ca.n[7] = 16384;
  ca.s[8] = W1;   ca.d[8] = cW1;  ca.n[8] = 32768;
  ca.s[9] = W2;   ca.d[9] = cW2;  ca.n[9] = 32768;
  cvt_weights<<<dim3(32, 10), blk256, 0, stream>>>(ca);
  concat_bias4<<<dim3(1), dim3(128), 0, stream>>>(bqv, bkv, bvv, bsk, bias512);
  cvt_x<<<dim3((N * 128 / 8 + 255) / 256), blk256, 0, stream>>>(x, xb, N * 128);

  // CSR build
  hipMemsetAsync(deg, 0, (size_t)N * sizeof(int), stream);
  count_deg<<<dim3((E + 255) / 256), blk256, 0, stream>>>(dstI, deg, E);
  scan_pass1<<<dim3(SB), blk256, 0, stream>>>(deg, bsum, N);
  scan_pass2<<<dim3(1), dim3(1024), 0, stream>>>(bsum, SB);
  scan_pass3<<<dim3(SB), blk256, 0, stream>>>(deg, bsum, row_start, cursor, N, E);
  fill_edges<<<dim3((E + 255) / 256), blk256, 0, stream>>>(dstI, srcI, cursor, edge_src, E);

  // fused tconv projections: all 512 cols -> qkvb bf16 (q|k|v|xr)
  gemm_direct<128><<<dim3(GXM, 4), blk256, 0, stream>>>(xb, cWq, bias512,
                                                        qkvb, 512, 512, nullptr, 0,
                                                        N, 512, 0);

  // edge attention + gate + LN  -> x1 (fp32) + x1b (bf16)
  tconv_attn<<<dim3((N * H + 255) / 256), blk256, 0, stream>>>(qkvb, row_start, edge_src, wa, N);
  gate_ln<<<dim3((N + 3) / 4), blk256, 0, stream>>>(x, wa, qkvb, Wbeta, x1, x1b, N);

  // global MHA: fused K|V projection (N x 256, bf16 out; aliases qkvb which is now dead)
  gemm_direct<128><<<dim3(GXM, 2), blk256, 0, stream>>>(x1b, cNgK, ngb + 128,
                                                        kv16, 256, 256, nullptr, 0,
                                                        N, 256, 0);
  gemm_small<<<dim3(64), dim3(128), 0, stream>>>(gh, ngw, ngb, Qg, 64);
  glob_part<<<dim3(512, NCH), dim3(64), 0, stream>>>(Qg, kv16, Plog, pm, ps, pacc, MAXN);
  glob_merge<<<dim3(512), dim3(64), 0, stream>>>(pm, ps, pacc, Og, m_gl, is_gl);
  pker2<<<dim3((MAXN + 255) / 256, 8), blk256, 0, stream>>>(Plog, m_gl, is_gl, Pbuf, MAXN);
  regk<<<dim3(8), blk256, 0, stream>>>(Pbuf, offb, MAXN);
  regfin<<<dim3(1), dim3(64), 0, stream>>>(offb, outreg);

  gemm_small<<<dim3(64), dim3(128), 0, stream>>>(Og, ngow, ngob, gout, 64);
  ln_add<<<dim3(16), blk256, 0, stream>>>(gh, gout, outgh, nullptr, 64);   // new global_h

  // nodes attend to global tokens: fused Qn-proj -> attention -> out-proj
  gemm_small2<<<dim3(128), dim3(128), 0, stream>>>(outgh,
                                                   gnw + 128 * 128, gnb + 128, Kg,
                                                   gnw + 256 * 128, gnb + 256, Vg);
  gemm_node<<<dim3(GXM), blk256, 0, stream>>>(x1b, cGnQ, gnb, Kg, Vg, cGnO, gnob,
                                              wa, N, MAXN);
  ln_add<<<dim3((N + 3) / 4), blk256, 0, stream>>>(x1, wa, x1, x1b, N);   // x2 fp32 + bf16

  // fused FF + final LN -> d_out x
  gemm_ff<<<dim3(GXM), blk256, 0, stream>>>(x1b, cW1, b1v, cW2, b2v, ff2o, N);
  ln_add<<<dim3((N + 3) / 4), blk256, 0, stream>>>(x1, ff2o, outx, nullptr, N);
}

// Round 15
// 350.233 us; speedup vs baseline: 1.1016x; 1.0278x over previous
//
#include <hip/hip_runtime.h>
#include <math.h>

#define D 128
#define H 8
#define NGT 8
#define LSTOK 4   // n_global_tokens_global (fixed by problem)
#define NCH 4     // node chunks for glob_part

typedef short bf16x8 __attribute__((ext_vector_type(8)));
typedef float f32x4  __attribute__((ext_vector_type(4)));

__device__ __forceinline__ short f2bf(float f) {
  union { float f; unsigned u; } v; v.f = f;
  unsigned r = v.u + 0x7FFFu + ((v.u >> 16) & 1u);   // RNE
  return (short)(r >> 16);
}
__device__ __forceinline__ float bf2f(short s) {
  union { unsigned u; float f; } v;
  v.u = ((unsigned)(unsigned short)s) << 16;
  return v.f;
}
__device__ __forceinline__ float4 bf4(bf16x8 v, int lo) {
  return make_float4(bf2f(v[lo]), bf2f(v[lo + 1]), bf2f(v[lo + 2]), bf2f(v[lo + 3]));
}
__device__ __forceinline__ unsigned pk2(float a, float b) {
  return ((unsigned)(unsigned short)f2bf(b) << 16) | (unsigned short)f2bf(a);
}

__device__ __forceinline__ float dot4(float4 a, float4 b) {
  return a.x*b.x + a.y*b.y + a.z*b.z + a.w*b.w;
}
__device__ __forceinline__ float4 scale_madd(float4 a, float sc, float4 v, float p) {
  return make_float4(fmaf(p, v.x, a.x*sc), fmaf(p, v.y, a.y*sc),
                     fmaf(p, v.z, a.z*sc), fmaf(p, v.w, a.w*sc));
}
__device__ __forceinline__ float4 comb4(float4 a, float e1, float4 c, float e2) {
  return make_float4(a.x*e1 + c.x*e2, a.y*e1 + c.y*e2, a.z*e1 + c.z*e2, a.w*e1 + c.w*e2);
}
__device__ __forceinline__ float4 shfl_xor4(float4 v, int off) {
  return make_float4(__shfl_xor(v.x, off), __shfl_xor(v.y, off),
                     __shfl_xor(v.z, off), __shfl_xor(v.w, off));
}

// ---------------- weight fp32 -> bf16 conversion (one-shot, 10 matrices) ----------------
struct CvtArgs {
  const float* s[10];
  short*       d[10];
  int          n[10];
};

__global__ void cvt_weights(CvtArgs a) {
  int which = blockIdx.y;
  const float* s = a.s[which];
  short* d = a.d[which];
  int n = a.n[which];
  int i = (blockIdx.x * 256 + threadIdx.x) * 4;
  if (i + 3 < n) {
    float4 v = *(const float4*)(s + i);
    d[i]     = f2bf(v.x);
    d[i + 1] = f2bf(v.y);
    d[i + 2] = f2bf(v.z);
    d[i + 3] = f2bf(v.w);
  }
}

// x fp32 -> bf16 (n divisible by 8)
__global__ void cvt_x(const float* __restrict__ s, short* __restrict__ d, int n) {
  int i = (blockIdx.x * 256 + threadIdx.x) * 8;
  if (i + 7 < n) {
    float4 a = *(const float4*)(s + i);
    float4 b = *(const float4*)(s + i + 4);
    bf16x8 v;
    v[0] = f2bf(a.x); v[1] = f2bf(a.y); v[2] = f2bf(a.z); v[3] = f2bf(a.w);
    v[4] = f2bf(b.x); v[5] = f2bf(b.y); v[6] = f2bf(b.z); v[7] = f2bf(b.w);
    *(bf16x8*)(d + i) = v;
  }
}

__global__ void concat_bias4(const float* __restrict__ b0, const float* __restrict__ b1,
                             const float* __restrict__ b2, const float* __restrict__ b3,
                             float* __restrict__ out) {
  int t = threadIdx.x;
  out[t] = b0[t]; out[128 + t] = b1[t]; out[256 + t] = b2[t]; out[384 + t] = b3[t];
}

// ---------------- direct MFMA GEMM (no staging LDS; LDS only for bf16 epilogue) -------
#define EPST 72   // LDS epilogue row stride in shorts (144B, 16B-aligned)
template<int K>
__global__ void __launch_bounds__(256) gemm_direct(const short* __restrict__ A,
    const short* __restrict__ Wb, const float* __restrict__ bias,
    short* __restrict__ out16, int C16, int s16,
    float* __restrict__ out32, int s32,
    int Nrows, int Ccols, int relu)
{
  __shared__ short eplds[4][64 * EPST];
  const int t = threadIdx.x;
  const int wid = t >> 6, lane = t & 63;
  const int rowBase = blockIdx.x * 128 + (wid >> 1) * 64;
  const int colBase = blockIdx.y * 128 + (wid & 1) * 64;
  const int lrow = lane & 15;
  const int lk = (lane >> 4) * 8;

  f32x4 acc[4][4];
  f32x4 z4 = {0.f, 0.f, 0.f, 0.f};
#pragma unroll
  for (int m = 0; m < 4; m++)
#pragma unroll
    for (int n = 0; n < 4; n++) acc[m][n] = z4;

  const short* ap[4];
#pragma unroll
  for (int m = 0; m < 4; ++m) {
    int ar = rowBase + m * 16 + lrow;
    if (ar >= Nrows) ar = Nrows - 1;
    ap[m] = A + (size_t)ar * K + lk;
  }
  const short* wp[4];
#pragma unroll
  for (int n = 0; n < 4; ++n)
    wp[n] = Wb + (size_t)(colBase + n * 16 + lrow) * K + lk;

#pragma unroll
  for (int kb = 0; kb < K; kb += 32) {
    bf16x8 af[4], bfr[4];
#pragma unroll
    for (int m = 0; m < 4; ++m) af[m] = *(const bf16x8*)(ap[m] + kb);
#pragma unroll
    for (int n = 0; n < 4; ++n) bfr[n] = *(const bf16x8*)(wp[n] + kb);
#pragma unroll
    for (int m = 0; m < 4; ++m)
#pragma unroll
      for (int n = 0; n < 4; ++n)
        acc[m][n] = __builtin_amdgcn_mfma_f32_16x16x32_bf16(af[m], bfr[n], acc[m][n], 0, 0, 0);
  }

  const int ccol = lane & 15;
  const int rquad = (lane >> 4) * 4;
  if (colBase < C16) {
    short* lds = eplds[wid];
#pragma unroll
    for (int n = 0; n < 4; ++n) {
      float bb = bias[colBase + n * 16 + ccol];
      int col = n * 16 + ccol;
#pragma unroll
      for (int m = 0; m < 4; ++m) {
        int r0 = m * 16 + rquad;
#pragma unroll
        for (int r = 0; r < 4; ++r) {
          float v = acc[m][n][r] + bb;
          if (relu) v = fmaxf(v, 0.f);
          lds[(r0 + r) * EPST + col] = f2bf(v);
        }
      }
    }
    const int jr = lane >> 3, jc = lane & 7;
#pragma unroll
    for (int i = 0; i < 8; ++i) {
      int row = i * 8 + jr;
      int gr = rowBase + row;
      if (gr < Nrows) {
        bf16x8 v = *(const bf16x8*)(lds + row * EPST + jc * 8);
        *(bf16x8*)(out16 + (size_t)gr * s16 + colBase + jc * 8) = v;
      }
    }
  } else {
#pragma unroll
    for (int n = 0; n < 4; ++n) {
      int col = colBase + n * 16 + ccol;
      float bb = bias[col];
#pragma unroll
      for (int m = 0; m < 4; ++m) {
        int row0 = rowBase + m * 16 + rquad;
#pragma unroll
        for (int r = 0; r < 4; ++r) {
          int gr = row0 + r;
          if (gr < Nrows) {
            float v = acc[m][n][r] + bb;
            if (relu) v = fmaxf(v, 0.f);
            out32[(size_t)gr * s32 + (col - C16)] = v;
          }
        }
      }
    }
  }
}

// ---------------- fused FF: out = relu(A@W1^T+b1)@W2^T+b2 (ff1 via LDS) ----------------
#define FFST 264   // LDS row stride in shorts for the 256-wide ff1 tile
__global__ void __launch_bounds__(256) gemm_ff(const short* __restrict__ A,
    const short* __restrict__ W1b, const float* __restrict__ b1,
    const short* __restrict__ W2b, const float* __restrict__ b2,
    float* __restrict__ out, int Nrows)
{
  __shared__ short flds[128 * FFST];
  const int t = threadIdx.x;
  const int wid = t >> 6, lane = t & 63;
  const int rowL = (wid >> 1) * 64;
  const int rowBase = blockIdx.x * 128 + rowL;
  const int lrow = lane & 15;
  const int lk = (lane >> 4) * 8;
  const int ccol = lane & 15;
  const int rquad = (lane >> 4) * 4;
  f32x4 z4 = {0.f, 0.f, 0.f, 0.f};

  const short* ap[4];
#pragma unroll
  for (int m = 0; m < 4; ++m) {
    int ar = rowBase + m * 16 + lrow;
    if (ar >= Nrows) ar = Nrows - 1;
    ap[m] = A + (size_t)ar * 128 + lk;
  }

  // ---- stage A: ff1 tile (128x256) in two 128-col passes -> LDS bf16 (relu'd) ----
  for (int cb = 0; cb < 2; ++cb) {
    int colBase = cb * 128 + (wid & 1) * 64;
    f32x4 acc[4][4];
#pragma unroll
    for (int m = 0; m < 4; m++)
#pragma unroll
      for (int n = 0; n < 4; n++) acc[m][n] = z4;
    const short* wp[4];
#pragma unroll
    for (int n = 0; n < 4; ++n)
      wp[n] = W1b + (size_t)(colBase + n * 16 + lrow) * 128 + lk;
#pragma unroll
    for (int kb = 0; kb < 128; kb += 32) {
      bf16x8 af[4], bfr[4];
#pragma unroll
      for (int m = 0; m < 4; ++m) af[m] = *(const bf16x8*)(ap[m] + kb);
#pragma unroll
      for (int n = 0; n < 4; ++n) bfr[n] = *(const bf16x8*)(wp[n] + kb);
#pragma unroll
      for (int m = 0; m < 4; ++m)
#pragma unroll
        for (int n = 0; n < 4; ++n)
          acc[m][n] = __builtin_amdgcn_mfma_f32_16x16x32_bf16(af[m], bfr[n], acc[m][n], 0, 0, 0);
    }
#pragma unroll
    for (int n = 0; n < 4; ++n) {
      int col = colBase + n * 16 + ccol;
      float bb = b1[col];
#pragma unroll
      for (int m = 0; m < 4; ++m) {
        int r0 = rowL + m * 16 + rquad;
#pragma unroll
        for (int r = 0; r < 4; ++r) {
          float v = fmaxf(acc[m][n][r] + bb, 0.f);
          flds[(r0 + r) * FFST + col] = f2bf(v);
        }
      }
    }
  }
  __syncthreads();

  // ---- stage B: out(128x128) = ff1 @ W2^T + b2, K=256, A from LDS ----
  {
    int colBase = (wid & 1) * 64;
    f32x4 acc[4][4];
#pragma unroll
    for (int m = 0; m < 4; m++)
#pragma unroll
      for (int n = 0; n < 4; n++) acc[m][n] = z4;
    const short* wp[4];
#pragma unroll
    for (int n = 0; n < 4; ++n)
      wp[n] = W2b + (size_t)(colBase + n * 16 + lrow) * 256 + lk;
#pragma unroll
    for (int kb = 0; kb < 256; kb += 32) {
      bf16x8 af[4], bfr[4];
#pragma unroll
      for (int m = 0; m < 4; ++m)
        af[m] = *(const bf16x8*)(flds + (rowL + m * 16 + lrow) * FFST + kb + lk);
#pragma unroll
      for (int n = 0; n < 4; ++n) bfr[n] = *(const bf16x8*)(wp[n] + kb);
#pragma unroll
      for (int m = 0; m < 4; ++m)
#pragma unroll
        for (int n = 0; n < 4; ++n)
          acc[m][n] = __builtin_amdgcn_mfma_f32_16x16x32_bf16(af[m], bfr[n], acc[m][n], 0, 0, 0);
    }
#pragma unroll
    for (int n = 0; n < 4; ++n) {
      int col = colBase + n * 16 + ccol;
      float bb = b2[col];
#pragma unroll
      for (int m = 0; m < 4; ++m) {
        int row0 = rowBase + m * 16 + rquad;
#pragma unroll
        for (int r = 0; r < 4; ++r) {
          int gr = row0 + r;
          if (gr < Nrows) out[(size_t)gr * 128 + col] = acc[m][n][r] + bb;
        }
      }
    }
  }
}

// ------- fused node path (64-row tiles): Q=A@GnQ^T+b -> 8-tok attn -> On@GnO^T+b ------
// kg/vg h-major (stride 132 floats): conflict-free. LDS 34.3KB -> 4 blocks/CU.
#define QST 136
#define KVST 132
__global__ void __launch_bounds__(256) gemm_node(const short* __restrict__ A,
    const short* __restrict__ GnQb, const float* __restrict__ gnbq,
    const float* __restrict__ Kg, const float* __restrict__ Vg,
    const short* __restrict__ GnOb, const float* __restrict__ gnbo,
    float* __restrict__ out, int Nrows, int MAXN)
{
  __shared__ short qlds[64 * QST];
  __shared__ float kg[2][NGT * KVST];
  __shared__ float vg[2][NGT * KVST];
  const int t = threadIdx.x;
  const int wid = t >> 6, lane = t & 63;
  const int rowL = (wid >> 1) * 32;
  const int n0 = blockIdx.x * 64;
  const int rowBase = n0 + rowL;
  const int colBase = (wid & 1) * 64;
  const int lrow = lane & 15;
  const int lk = (lane >> 4) * 8;
  const int ccol = lane & 15;
  const int rquad = (lane >> 4) * 4;
  f32x4 z4 = {0.f, 0.f, 0.f, 0.f};

  // stage K/V for the (up to 2) batches this block touches; transpose to h-major
  int b0 = n0 / MAXN;
  int nlast = n0 + 63; if (nlast >= Nrows) nlast = Nrows - 1;
  int bLast = nlast / MAXN;
  int nb = (bLast != b0) ? 2 : 1;
  for (int bi = 0; bi < nb; ++bi) {
    size_t gb = (size_t)((b0 + bi) * NGT) * 128;
    int i = t * 4;                 // 256 thr x 4 floats = 1024 = 8 tokens x 128
    int tk = i >> 7, d = i & 127;
    int li = (d >> 4) * KVST + tk * 16 + (d & 15);
    *(float4*)&kg[bi][li] = *(const float4*)(Kg + gb + i);
    *(float4*)&vg[bi][li] = *(const float4*)(Vg + gb + i);
  }

  // ---- stage A: Q tile (64x128) = A @ GnQ^T + bias -> qlds bf16 ----
  {
    f32x4 acc[2][4];
#pragma unroll
    for (int m = 0; m < 2; m++)
#pragma unroll
      for (int n = 0; n < 4; n++) acc[m][n] = z4;
    const short* ap[2];
#pragma unroll
    for (int m = 0; m < 2; ++m) {
      int ar = rowBase + m * 16 + lrow;
      if (ar >= Nrows) ar = Nrows - 1;
      ap[m] = A + (size_t)ar * 128 + lk;
    }
    const short* wp[4];
#pragma unroll
    for (int n = 0; n < 4; ++n)
      wp[n] = GnQb + (size_t)(colBase + n * 16 + lrow) * 128 + lk;
#pragma unroll
    for (int kb = 0; kb < 128; kb += 32) {
      bf16x8 af[2], bfr[4];
#pragma unroll
      for (int m = 0; m < 2; ++m) af[m] = *(const bf16x8*)(ap[m] + kb);
#pragma unroll
      for (int n = 0; n < 4; ++n) bfr[n] = *(const bf16x8*)(wp[n] + kb);
#pragma unroll
      for (int m = 0; m < 2; ++m)
#pragma unroll
        for (int n = 0; n < 4; ++n)
          acc[m][n] = __builtin_amdgcn_mfma_f32_16x16x32_bf16(af[m], bfr[n], acc[m][n], 0, 0, 0);
    }
#pragma unroll
    for (int n = 0; n < 4; ++n) {
      int col = colBase + n * 16 + ccol;
      float bb = gnbq[col];
#pragma unroll
      for (int m = 0; m < 2; ++m) {
        int r0 = rowL + m * 16 + rquad;
#pragma unroll
        for (int r = 0; r < 4; ++r)
          qlds[(r0 + r) * QST + col] = f2bf(acc[m][n][r] + bb);
      }
    }
  }
  __syncthreads();

  // ---- stage B: per-(row,h) attention over 8 tokens; On overwrites Q slot ----
#pragma unroll
  for (int u = 0; u < 2; ++u) {
    int unit = t + u * 256;            // 0..511
    int row = unit >> 3, h = unit & 7;
    int grow = n0 + row;
    if (grow < Nrows) {
      int bi = (grow / MAXN) - b0;
      short* qp = qlds + row * QST + h * 16;
      bf16x8 qa = *(const bf16x8*)(qp);
      bf16x8 qb = *(const bf16x8*)(qp + 8);
      float4 q0 = bf4(qa, 0), q1 = bf4(qa, 4), q2 = bf4(qb, 0), q3 = bf4(qb, 4);
      const float* kh = &kg[bi][h * KVST];
      const float* vh = &vg[bi][h * KVST];
      float l[NGT];
      float mx = -3.0e38f;
#pragma unroll
      for (int tk = 0; tk < NGT; tk++) {
        const float4* k4 = (const float4*)(kh + tk * 16);
        float d = dot4(q0, k4[0]) + dot4(q1, k4[1]) + dot4(q2, k4[2]) + dot4(q3, k4[3]);
        l[tk] = d * 0.25f;
        mx = fmaxf(mx, l[tk]);
      }
      float s = 0.f;
#pragma unroll
      for (int tk = 0; tk < NGT; tk++) { l[tk] = expf(l[tk] - mx); s += l[tk]; }
      float inv = 1.f / s;
      float4 a0 = make_float4(0, 0, 0, 0), a1 = a0, a2 = a0, a3 = a0;
#pragma unroll
      for (int tk = 0; tk < NGT; tk++) {
        float p = l[tk] * inv;
        const float4* v4 = (const float4*)(vh + tk * 16);
        a0 = scale_madd(a0, 1.f, v4[0], p);
        a1 = scale_madd(a1, 1.f, v4[1], p);
        a2 = scale_madd(a2, 1.f, v4[2], p);
        a3 = scale_madd(a3, 1.f, v4[3], p);
      }
      unsigned* o = (unsigned*)qp;
      o[0] = pk2(a0.x, a0.y); o[1] = pk2(a0.z, a0.w);
      o[2] = pk2(a1.x, a1.y); o[3] = pk2(a1.z, a1.w);
      o[4] = pk2(a2.x, a2.y); o[5] = pk2(a2.z, a2.w);
      o[6] = pk2(a3.x, a3.y); o[7] = pk2(a3.z, a3.w);
    }
  }
  __syncthreads();

  // ---- stage C: out(64x128) = On @ GnO^T + bias (fp32, coalesced) ----
  {
    f32x4 acc[2][4];
#pragma unroll
    for (int m = 0; m < 2; m++)
#pragma unroll
      for (int n = 0; n < 4; n++) acc[m][n] = z4;
    const short* wp[4];
#pragma unroll
    for (int n = 0; n < 4; ++n)
      wp[n] = GnOb + (size_t)(colBase + n * 16 + lrow) * 128 + lk;
#pragma unroll
    for (int kb = 0; kb < 128; kb += 32) {
      bf16x8 af[2], bfr[4];
#pragma unroll
      for (int m = 0; m < 2; ++m)
        af[m] = *(const bf16x8*)(qlds + (rowL + m * 16 + lrow) * QST + kb + lk);
#pragma unroll
      for (int n = 0; n < 4; ++n) bfr[n] = *(const bf16x8*)(wp[n] + kb);
#pragma unroll
      for (int m = 0; m < 2; ++m)
#pragma unroll
        for (int n = 0; n < 4; ++n)
          acc[m][n] = __builtin_amdgcn_mfma_f32_16x16x32_bf16(af[m], bfr[n], acc[m][n], 0, 0, 0);
    }
#pragma unroll
    for (int n = 0; n < 4; ++n) {
      int col = colBase + n * 16 + ccol;
      float bb = gnbo[col];
#pragma unroll
      for (int m = 0; m < 2; ++m) {
        int row0 = rowBase + m * 16 + rquad;
#pragma unroll
        for (int r = 0; r < 4; ++r) {
          int gr = row0 + r;
          if (gr < Nrows) out[(size_t)gr * 128 + col] = acc[m][n][r] + bb;
        }
      }
    }
  }
}

// small GEMM (M rows <= 64, K=C=128): one block per row
__global__ void gemm_small(const float* __restrict__ A, const float* __restrict__ W,
                           const float* __restrict__ bias, float* __restrict__ out, int M)
{
  int r = blockIdx.x;
  int c = threadIdx.x;
  __shared__ float as[128];
  as[c] = A[(size_t)r * 128 + c];
  __syncthreads();
  float acc = bias[c];
  const float* wr = W + (size_t)c * 128;
#pragma unroll 4
  for (int k = 0; k < 128; k++) acc += as[k] * wr[k];
  out[(size_t)r * 128 + c] = acc;
}

// two small GEMMs in one launch (grid 128: blocks 0..63 -> {W0,b0,o0}, 64..127 -> {W1,b1,o1})
__global__ void gemm_small2(const float* __restrict__ A,
                            const float* __restrict__ W0, const float* __restrict__ b0, float* __restrict__ o0,
                            const float* __restrict__ W1, const float* __restrict__ b1, float* __restrict__ o1)
{
  int which = blockIdx.x >> 6;
  int r = blockIdx.x & 63;
  const float* W = which ? W1 : W0;
  const float* bias = which ? b1 : b0;
  float* out = which ? o1 : o0;
  int c = threadIdx.x;
  __shared__ float as[128];
  as[c] = A[(size_t)r * 128 + c];
  __syncthreads();
  float acc = bias[c];
  const float* wr = W + (size_t)c * 128;
#pragma unroll 4
  for (int k = 0; k < 128; k++) acc += as[k] * wr[k];
  out[(size_t)r * 128 + c] = acc;
}

// ---------------- CSR build ----------------
__global__ void count_deg(const int* __restrict__ dst, int* __restrict__ deg, int E) {
  int e = blockIdx.x * 256 + threadIdx.x;
  if (e < E) atomicAdd(&deg[dst[e]], 1);
}

__global__ void scan_pass1(const int* __restrict__ deg, int* __restrict__ bsum, int N) {
  int t = threadIdx.x, lane = t & 63, wid = t >> 6;
  int idx = blockIdx.x * 1024 + t * 4;
  int4 v = {0, 0, 0, 0};
  if (idx + 3 < N) v = *(const int4*)(deg + idx);
  else {
    if (idx < N) v.x = deg[idx];
    if (idx + 1 < N) v.y = deg[idx + 1];
    if (idx + 2 < N) v.z = deg[idx + 2];
    if (idx + 3 < N) v.w = deg[idx + 3];
  }
  int s = v.x + v.y + v.z + v.w;
#pragma unroll
  for (int off = 32; off >= 1; off >>= 1) s += __shfl_xor(s, off);
  __shared__ int ws[4];
  if (lane == 0) ws[wid] = s;
  __syncthreads();
  if (t == 0) bsum[blockIdx.x] = ws[0] + ws[1] + ws[2] + ws[3];
}

__global__ void scan_pass2(int* __restrict__ bsum, int SB) {
  __shared__ int sh[1024];
  int t = threadIdx.x;
  sh[t] = (t < SB) ? bsum[t] : 0;
  __syncthreads();
  for (int off = 1; off < 1024; off <<= 1) {
    int v = (t >= off) ? sh[t - off] : 0;
    __syncthreads();
    sh[t] += v;
    __syncthreads();
  }
  if (t < SB) bsum[t] = (t == 0) ? 0 : sh[t - 1];
}

__global__ void scan_pass3(const int* __restrict__ deg, const int* __restrict__ bsum,
                           int* __restrict__ row_start, int* __restrict__ cursor,
                           int N, int E)
{
  int t = threadIdx.x, lane = t & 63, wid = t >> 6;
  int idx = blockIdx.x * 1024 + t * 4;
  int4 v = {0, 0, 0, 0};
  if (idx + 3 < N) v = *(const int4*)(deg + idx);
  else {
    if (idx < N) v.x = deg[idx];
    if (idx + 1 < N) v.y = deg[idx + 1];
    if (idx + 2 < N) v.z = deg[idx + 2];
    if (idx + 3 < N) v.w = deg[idx + 3];
  }
  int ts = v.x + v.y + v.z + v.w;
  int x = ts;
#pragma unroll
  for (int off = 1; off < 64; off <<= 1) {
    int y = __shfl_up(x, off);
    if (lane >= off) x += y;
  }
  __shared__ int ws[4];
  if (lane == 63) ws[wid] = x;
  __syncthreads();
  int woff = 0;
  for (int i = 0; i < wid; i++) woff += ws[i];
  int p = bsum[blockIdx.x] + woff + (x - ts);
  if (idx < N)     { row_start[idx] = p; cursor[idx] = p; }     p += v.x;
  if (idx + 1 < N) { row_start[idx + 1] = p; cursor[idx + 1] = p; } p += v.y;
  if (idx + 2 < N) { row_start[idx + 2] = p; cursor[idx + 2] = p; } p += v.z;
  if (idx + 3 < N) { row_start[idx + 3] = p; cursor[idx + 3] = p; }
  if (blockIdx.x == 0 && t == 0) row_start[N] = E;
}

__global__ void fill_edges(const int* __restrict__ dst, const int* __restrict__ src,
                           int* __restrict__ cursor, int* __restrict__ edge_src, int E) {
  int e = blockIdx.x * 256 + threadIdx.x;
  if (e < E) {
    int p = atomicAdd(&cursor[dst[e]], 1);
    edge_src[p] = src[e];
  }
}

// ---------------- tconv edge attention: q|k|v|xr bf16 (qkvb stride 512) ----------------
__global__ void tconv_attn(const short* __restrict__ qkvb,
                           const int* __restrict__ row_start,
                           const int* __restrict__ edge_src,
                           float* __restrict__ out, int N)
{
  int gid = blockIdx.x * 256 + threadIdx.x;
  if (gid >= N * H) return;
  int n = gid >> 3, h = gid & 7;
  const short* qp = qkvb + (size_t)n * 512 + h * 16;
  bf16x8 qa = *(const bf16x8*)(qp);
  bf16x8 qb = *(const bf16x8*)(qp + 8);
  float4 q0 = bf4(qa, 0), q1 = bf4(qa, 4), q2 = bf4(qb, 0), q3 = bf4(qb, 4);
  int e0 = row_start[n], e1 = row_start[n + 1];

  float mA = -3.0e38f, sA = 0.f;
  float4 A0 = make_float4(0, 0, 0, 0), A1 = A0, A2 = A0, A3 = A0;
  float mB = -3.0e38f, sB = 0.f;
  float4 B0 = A0, B1 = A0, B2 = A0, B3 = A0;

  int ei = e0;
  for (; ei + 1 < e1; ei += 2) {
    int sn0 = edge_src[ei], sn1 = edge_src[ei + 1];
    const short* kp0 = qkvb + (size_t)sn0 * 512 + 128 + h * 16;
    const short* kp1 = qkvb + (size_t)sn1 * 512 + 128 + h * 16;
    bf16x8 k00 = *(const bf16x8*)(kp0);
    bf16x8 k01 = *(const bf16x8*)(kp0 + 8);
    bf16x8 k10 = *(const bf16x8*)(kp1);
    bf16x8 k11 = *(const bf16x8*)(kp1 + 8);
    float d0 = (dot4(q0, bf4(k00, 0)) + dot4(q1, bf4(k00, 4))
              + dot4(q2, bf4(k01, 0)) + dot4(q3, bf4(k01, 4))) * 0.25f;
    float d1 = (dot4(q0, bf4(k10, 0)) + dot4(q1, bf4(k10, 4))
              + dot4(q2, bf4(k11, 0)) + dot4(q3, bf4(k11, 4))) * 0.25f;
    bf16x8 v00 = *(const bf16x8*)(kp0 + 128);
    bf16x8 v01 = *(const bf16x8*)(kp0 + 136);
    bf16x8 v10 = *(const bf16x8*)(kp1 + 128);
    bf16x8 v11 = *(const bf16x8*)(kp1 + 136);
    float mn0 = fmaxf(mA, d0);
    float sc0 = expf(mA - mn0), p0 = expf(d0 - mn0);
    A0 = scale_madd(A0, sc0, bf4(v00, 0), p0);
    A1 = scale_madd(A1, sc0, bf4(v00, 4), p0);
    A2 = scale_madd(A2, sc0, bf4(v01, 0), p0);
    A3 = scale_madd(A3, sc0, bf4(v01, 4), p0);
    sA = sA * sc0 + p0; mA = mn0;
    float mn1 = fmaxf(mB, d1);
    float sc1 = expf(mB - mn1), p1 = expf(d1 - mn1);
    B0 = scale_madd(B0, sc1, bf4(v10, 0), p1);
    B1 = scale_madd(B1, sc1, bf4(v10, 4), p1);
    B2 = scale_madd(B2, sc1, bf4(v11, 0), p1);
    B3 = scale_madd(B3, sc1, bf4(v11, 4), p1);
    sB = sB * sc1 + p1; mB = mn1;
  }
  if (ei < e1) {
    int sn0 = edge_src[ei];
    const short* kp0 = qkvb + (size_t)sn0 * 512 + 128 + h * 16;
    bf16x8 k00 = *(const bf16x8*)(kp0);
    bf16x8 k01 = *(const bf16x8*)(kp0 + 8);
    float d0 = (dot4(q0, bf4(k00, 0)) + dot4(q1, bf4(k00, 4))
              + dot4(q2, bf4(k01, 0)) + dot4(q3, bf4(k01, 4))) * 0.25f;
    bf16x8 v00 = *(const bf16x8*)(kp0 + 128);
    bf16x8 v01 = *(const bf16x8*)(kp0 + 136);
    float mn0 = fmaxf(mA, d0);
    float sc0 = expf(mA - mn0), p0 = expf(d0 - mn0);
    A0 = scale_madd(A0, sc0, bf4(v00, 0), p0);
    A1 = scale_madd(A1, sc0, bf4(v00, 4), p0);
    A2 = scale_madd(A2, sc0, bf4(v01, 0), p0);
    A3 = scale_madd(A3, sc0, bf4(v01, 4), p0);
    sA = sA * sc0 + p0; mA = mn0;
  }
  float mn = fmaxf(mA, mB);
  float eA = expf(mA - mn), eB = expf(mB - mn);
  float s = sA * eA + sB * eB;
  float4 a0 = comb4(A0, eA, B0, eB);
  float4 a1 = comb4(A1, eA, B1, eB);
  float4 a2 = comb4(A2, eA, B2, eB);
  float4 a3 = comb4(A3, eA, B3, eB);
  float inv = 1.f / (s + 1e-16f);
  float4* o4 = (float4*)(out + (size_t)n * 128 + h * 16);
  o4[0] = make_float4(a0.x * inv, a0.y * inv, a0.z * inv, a0.w * inv);
  o4[1] = make_float4(a1.x * inv, a1.y * inv, a1.z * inv, a1.w * inv);
  o4[2] = make_float4(a2.x * inv, a2.y * inv, a2.z * inv, a2.w * inv);
  o4[3] = make_float4(a3.x * inv, a3.y * inv, a3.z * inv, a3.w * inv);
}

// ---------------- gate + residual + LN -> x1 (fp32) + x1b (bf16); xr bf16 in qkvb ------
__global__ void gate_ln(const float* __restrict__ x, const float* __restrict__ att,
                        const short* __restrict__ qkvb, const float* __restrict__ Wb,
                        float* __restrict__ x1, short* __restrict__ x1b, int N)
{
  int wid = threadIdx.x >> 6, lane = threadIdx.x & 63;
  int n = blockIdx.x * 4 + wid;
  if (n >= N) return;
  size_t base = (size_t)n * 128 + lane * 2;
  float2 o = *(const float2*)(att + base);
  unsigned ru = *(const unsigned*)(qkvb + (size_t)n * 512 + 384 + lane * 2);
  float2 r = make_float2(bf2f((short)(ru & 0xFFFF)), bf2f((short)(ru >> 16)));
  float2 xv = *(const float2*)(x + base);
  float2 w0 = *(const float2*)(Wb + lane * 2);
  float2 w1 = *(const float2*)(Wb + 128 + lane * 2);
  float2 w2 = *(const float2*)(Wb + 256 + lane * 2);
  float ts = o.x * w0.x + o.y * w0.y + r.x * w1.x + r.y * w1.y
           + (o.x - r.x) * w2.x + (o.y - r.y) * w2.y;
#pragma unroll
  for (int mm = 32; mm >= 1; mm >>= 1) ts += __shfl_xor(ts, mm);
  float beta = 1.f / (1.f + expf(-ts));
  float2 y;
  y.x = xv.x + beta * r.x + (1.f - beta) * o.x;
  y.y = xv.y + beta * r.y + (1.f - beta) * o.y;
  float sm = y.x + y.y;
#pragma unroll
  for (int mm = 32; mm >= 1; mm >>= 1) sm += __shfl_xor(sm, mm);
  float mean = sm * (1.f / 128.f);
  float dx = y.x - mean, dy = y.y - mean;
  float vs = dx * dx + dy * dy;
#pragma unroll
  for (int mm = 32; mm >= 1; mm >>= 1) vs += __shfl_xor(vs, mm);
  float rstd = rsqrtf(vs * (1.f / 128.f) + 1e-5f);
  float ox = dx * rstd, oy = dy * rstd;
  *(float2*)(x1 + base) = make_float2(ox, oy);
  *(unsigned*)(x1b + base) = pk2(ox, oy);
}

// ---------------- out = LN(a + b); optional bf16 copy ----------------
__global__ void ln_add(const float* __restrict__ a, const float* __restrict__ b,
                       float* __restrict__ out, short* __restrict__ out16, int R)
{
  int wid = threadIdx.x >> 6, lane = threadIdx.x & 63;
  int r = blockIdx.x * 4 + wid;
  if (r >= R) return;
  size_t base = (size_t)r * 128 + lane * 2;
  float2 av = *(const float2*)(a + base);
  float2 bv = *(const float2*)(b + base);
  float2 y = make_float2(av.x + bv.x, av.y + bv.y);
  float sm = y.x + y.y;
#pragma unroll
  for (int mm = 32; mm >= 1; mm >>= 1) sm += __shfl_xor(sm, mm);
  float mean = sm * (1.f / 128.f);
  float dx = y.x - mean, dy = y.y - mean;
  float vs = dx * dx + dy * dy;
#pragma unroll
  for (int mm = 32; mm >= 1; mm >>= 1) vs += __shfl_xor(vs, mm);
  float rstd = rsqrtf(vs * (1.f / 128.f) + 1e-5f);
  float ox = dx * rstd, oy = dy * rstd;
  *(float2*)(out + base) = make_float2(ox, oy);
  if (out16) *(unsigned*)(out16 + base) = pk2(ox, oy);
}

// ---------------- glob attention, pass 1: partial online softmax over node chunks ------
__global__ void glob_part(const float* __restrict__ Qg, const short* __restrict__ kv,
                          float* __restrict__ Plog,
                          float* __restrict__ pm, float* __restrict__ ps,
                          float* __restrict__ pacc, int MAXN)
{
  int blk = blockIdx.x;                 // b*64 + g*8 + h
  int ch = blockIdx.y;
  int h = blk & 7, g = (blk >> 3) & 7, b = blk >> 6;
  int lane = threadIdx.x;
  const float4* q4 = (const float4*)(Qg + (size_t)(b * NGT + g) * 128 + h * 16);
  float4 q0 = q4[0], q1 = q4[1], q2 = q4[2], q3 = q4[3];
  int chunk = (MAXN + NCH - 1) / NCH;
  int n0 = ch * chunk;
  int n1 = n0 + chunk; if (n1 > MAXN) n1 = MAXN;
  float* plrow = (g >= LSTOK) ? Plog + (((size_t)(b * 4 + g - LSTOK)) * H + h) * MAXN : nullptr;
  float m = -3.0e38f, s = 0.f;
  float4 a0 = make_float4(0, 0, 0, 0), a1 = a0, a2 = a0, a3 = a0;
  for (int n = n0 + lane; n < n1; n += 64) {
    const short* kp = kv + ((size_t)(b * MAXN + n)) * 256 + h * 16;
    bf16x8 k0 = *(const bf16x8*)(kp);
    bf16x8 k1 = *(const bf16x8*)(kp + 8);
    float d = dot4(q0, bf4(k0, 0)) + dot4(q1, bf4(k0, 4))
            + dot4(q2, bf4(k1, 0)) + dot4(q3, bf4(k1, 4));
    d *= 0.25f;
    if (plrow) plrow[n] = d;
    float mn = fmaxf(m, d);
    float sc = expf(m - mn);
    float p = expf(d - mn);
    bf16x8 v0 = *(const bf16x8*)(kp + 128);
    bf16x8 v1 = *(const bf16x8*)(kp + 136);
    a0 = scale_madd(a0, sc, bf4(v0, 0), p);
    a1 = scale_madd(a1, sc, bf4(v0, 4), p);
    a2 = scale_madd(a2, sc, bf4(v1, 0), p);
    a3 = scale_madd(a3, sc, bf4(v1, 4), p);
    s = s * sc + p;
    m = mn;
  }
#pragma unroll
  for (int off = 32; off >= 1; off >>= 1) {
    float m2 = __shfl_xor(m, off);
    float s2 = __shfl_xor(s, off);
    float4 c0 = shfl_xor4(a0, off), c1 = shfl_xor4(a1, off);
    float4 c2 = shfl_xor4(a2, off), c3 = shfl_xor4(a3, off);
    float mn = fmaxf(m, m2);
    float e1 = expf(m - mn), e2 = expf(m2 - mn);
    s = s * e1 + s2 * e2;
    a0 = comb4(a0, e1, c0, e2);
    a1 = comb4(a1, e1, c1, e2);
    a2 = comb4(a2, e1, c2, e2);
    a3 = comb4(a3, e1, c3, e2);
    m = mn;
  }
  if (lane == 0) {
    int pi = blk * NCH + ch;
    pm[pi] = m; ps[pi] = s;
    float4* pa = (float4*)(pacc + (size_t)pi * 16);
    pa[0] = a0; pa[1] = a1; pa[2] = a2; pa[3] = a3;
  }
}

__global__ void glob_merge(const float* __restrict__ pm, const float* __restrict__ ps,
                           const float* __restrict__ pacc, float* __restrict__ Og,
                           float* __restrict__ m_gl, float* __restrict__ is_gl)
{
  int blk = blockIdx.x;
  int lane = threadIdx.x;
  float m = -3.0e38f;
#pragma unroll
  for (int c = 0; c < NCH; ++c) m = fmaxf(m, pm[blk * NCH + c]);
  float s = 0.f;
#pragma unroll
  for (int c = 0; c < NCH; ++c) s += ps[blk * NCH + c] * expf(pm[blk * NCH + c] - m);
  if (lane < 16) {
    float a = 0.f;
#pragma unroll
    for (int c = 0; c < NCH; ++c)
      a += pacc[(size_t)(blk * NCH + c) * 16 + lane] * expf(pm[blk * NCH + c] - m);
    int h = blk & 7, g = (blk >> 3) & 7, b = blk >> 6;
    Og[(size_t)(b * NGT + g) * 128 + h * 16 + lane] = a / s;
  }
  if (lane == 0) { m_gl[blk] = m; is_gl[blk] = 1.f / s; }
}

// ---------------- P rows from stored logits ----------------
__global__ void pker2(const float* __restrict__ Plog,
                      const float* __restrict__ m_gl, const float* __restrict__ is_gl,
                      float* __restrict__ P, int MAXN)
{
  int b = blockIdx.y;
  __shared__ float ms[32], iss[32];
  if (threadIdx.x < 32) {
    int g = threadIdx.x >> 3, h = threadIdx.x & 7;
    ms[threadIdx.x]  = m_gl[(b * NGT + LSTOK + g) * H + h];
    iss[threadIdx.x] = is_gl[(b * NGT + LSTOK + g) * H + h];
  }
  __syncthreads();
  int n = blockIdx.x * 256 + threadIdx.x;
  if (n >= MAXN) return;
#pragma unroll
  for (int g = 0; g < 4; g++) {
    float acc = 0.f;
#pragma unroll
    for (int h = 0; h < H; h++) {
      float l = Plog[(((size_t)(b * 4 + g)) * H + h) * MAXN + n];
      acc += expf(l - ms[g * 8 + h]) * iss[g * 8 + h];
    }
    P[(size_t)(b * 4 + g) * MAXN + n] = acc * 0.125f;
  }
}

// ---------------- reg: off-diagonal Gram of row-normalized P ----------------
__global__ void regk(const float* __restrict__ P, float* __restrict__ offb, int MAXN)
{
  int b = blockIdx.x;
  int t = threadIdx.x;
  float v[10];
#pragma unroll
  for (int i = 0; i < 10; i++) v[i] = 0.f;
  for (int n = t; n < MAXN; n += 256) {
    float p0 = P[(size_t)(b * 4 + 0) * MAXN + n];
    float p1 = P[(size_t)(b * 4 + 1) * MAXN + n];
    float p2 = P[(size_t)(b * 4 + 2) * MAXN + n];
    float p3 = P[(size_t)(b * 4 + 3) * MAXN + n];
    v[0] += p0; v[1] += p1; v[2] += p2; v[3] += p3;
    v[4] += p0 * p1; v[5] += p0 * p2; v[6] += p0 * p3;
    v[7] += p1 * p2; v[8] += p1 * p3; v[9] += p2 * p3;
  }
#pragma unroll
  for (int i = 0; i < 10; i++) {
    float x = v[i];
#pragma unroll
    for (int mm = 32; mm >= 1; mm >>= 1) x += __shfl_xor(x, mm);
    v[i] = x;
  }
  __shared__ float red[4][10];
  int wid = t >> 6, lane = t & 63;
  if (lane == 0)
    for (int i = 0; i < 10; i++) red[wid][i] = v[i];
  __syncthreads();
  if (t == 0) {
    float r[10];
    for (int i = 0; i < 10; i++) r[i] = red[0][i] + red[1][i] + red[2][i] + red[3][i];
    float r0 = r[0] + 1e-8f, r1 = r[1] + 1e-8f, r2 = r[2] + 1e-8f, r3 = r[3] + 1e-8f;
    float off = 2.f * (r[4] / (r0 * r1) + r[5] / (r0 * r2) + r[6] / (r0 * r3)
                     + r[7] / (r1 * r2) + r[8] / (r1 * r3) + r[9] / (r2 * r3));
    offb[b] = off * (1.f / 12.f);   // (Kt*Kt - Kt) = 12
  }
}

__global__ void regfin(const float* __restrict__ offb, float* __restrict__ out) {
  if (threadIdx.x == 0 && blockIdx.x == 0) {
    float s = 0.f;
    for (int i = 0; i < 8; i++) s += offb[i];
    *out = s * (1.f / 8.f);
  }
}

extern "C" void kernel_launch(void* const* d_in, const int* in_sizes, int n_in,
                              void* d_out, int out_size, void* d_ws, size_t ws_size,
                              hipStream_t stream)
{
  const float* x     = (const float*)d_in[0];
  const int*   ei    = (const int*)d_in[1];
  const float* gh    = (const float*)d_in[2];
  const float* Wq    = (const float*)d_in[6];
  const float* bqv   = (const float*)d_in[7];
  const float* Wk    = (const float*)d_in[8];
  const float* bkv   = (const float*)d_in[9];
  const float* Wv    = (const float*)d_in[10];
  const float* bvv   = (const float*)d_in[11];
  const float* Wsk   = (const float*)d_in[12];
  const float* bsk   = (const float*)d_in[13];
  const float* Wbeta = (const float*)d_in[14];
  const float* ngw   = (const float*)d_in[15];
  const float* ngb   = (const float*)d_in[16];
  const float* ngow  = (const float*)d_in[17];
  const float* ngob  = (const float*)d_in[18];
  const float* gnw   = (const float*)d_in[19];
  const float* gnb   = (const float*)d_in[20];
  const float* gnow  = (const float*)d_in[21];
  const float* gnob  = (const float*)d_in[22];
  const float* W1    = (const float*)d_in[23];
  const float* b1v   = (const float*)d_in[24];
  const float* W2    = (const float*)d_in[25];
  const float* b2v   = (const float*)d_in[26];

  const int N    = in_sizes[0] / D;   // 50000
  const int E    = in_sizes[1] / 2;   // 400000
  const int Bb   = 8;
  const int MAXN = N / Bb;            // 6250

  const int* srcI = ei;
  const int* dstI = ei + E;

  size_t NF = (size_t)N;
  size_t ND = NF * D;
  float* fw = (float*)d_ws;
  short* qkvb = (short*)fw;              // N x 512 bf16 (q|k|v|xr); later kv16 aliases
  short* kv16 = qkvb;                    // N x 256 bf16
  float* ff2o = fw + NF * 256;           // N x 128 f32
  float* x1   = fw + NF * 384;           // N x 128 f32
  short* x1b  = (short*)(fw + NF * 512); // N x 128 bf16
  float* misc = fw + NF * 576;
  float* Qg    = misc;                // 64*128
  float* Og    = Qg + 8192;
  float* gout  = Og + 8192;
  float* Kg    = gout + 8192;
  float* Vg    = Kg + 8192;
  float* m_gl  = Vg + 8192;           // 512
  float* is_gl = m_gl + 512;          // 512
  float* Pbuf  = is_gl + 512;         // 8*4*MAXN
  float* offb  = Pbuf + (size_t)Bb * 4 * MAXN;   // 8 (+pad)
  float* bias512 = offb + 16;         // 512
  float* Plog  = bias512 + 512;       // 4*8*8*MAXN floats
  float* pm    = Plog + (size_t)4 * H * Bb * MAXN;
  float* ps    = pm + 512 * NCH;
  float* pacc  = ps + 512 * NCH;      // 512*NCH*16
  int* deg       = (int*)(pacc + 512 * NCH * 16);
  int* row_start = deg + N;           // N+1
  int* cursor    = row_start + N + 1;
  int* bsum      = cursor + N;        // <=1024
  int* edge_src  = bsum + 1024;       // E
  short* wbase = (short*)((((uintptr_t)(edge_src + E)) + 15) & ~(uintptr_t)15);
  short* cWq  = wbase;            // 4 x 128x128 stacked -> 512x128
  short* cWk  = cWq  + 16384;
  short* cWv  = cWk  + 16384;
  short* cWsk = cWv  + 16384;
  short* cNgK = cWsk + 16384;     // 2 x 128x128 stacked -> 256x128
  short* cNgV = cNgK + 16384;
  short* cGnQ = cNgV + 16384;
  short* cGnO = cGnQ + 16384;
  short* cW1  = cGnO + 16384;     // 256x128
  short* cW2  = cW1  + 32768;     // 128x256
  short* xb   = cW2  + 32768;     // N x 128 bf16 (x converted)

  float* outx   = (float*)d_out;
  float* outgh  = outx + ND;                       // 8192
  float* outreg = outgh + (size_t)Bb * NGT * D;    // 1
  float* wa     = outx;   // scratch fp32 N x 128

  const int GXM = (N + 127) / 128;    // 391
  const int SB  = (N + 1023) / 1024;  // 49
  dim3 blk256(256);

  // one-shot weight conversion + bias concat + x conversion
  CvtArgs ca;
  ca.s[0] = Wq;   ca.d[0] = cWq;  ca.n[0] = 16384;
  ca.s[1] = Wk;   ca.d[1] = cWk;  ca.n[1] = 16384;
  ca.s[2] = Wv;   ca.d[2] = cWv;  ca.n[2] = 16384;
  ca.s[3] = Wsk;  ca.d[3] = cWsk; ca.n[3] = 16384;
  ca.s[4] = ngw + 128 * 128; ca.d[4] = cNgK; ca.n[4] = 16384;
  ca.s[5] = ngw + 256 * 128; ca.d[5] = cNgV; ca.n[5] = 16384;
  ca.s[6] = gnw;  ca.d[6] = cGnQ; ca.n[6] = 16384;
  ca.s[7] = gnow; ca.d[7] = cGnO; ca.n[7] = 16384;
  ca.s[8] = W1;   ca.d[8] = cW1;  ca.n[8] = 32768;
  ca.s[9] = W2;   ca.d[9] = cW2;  ca.n[9] = 32768;
  cvt_weights<<<dim3(32, 10), blk256, 0, stream>>>(ca);
  concat_bias4<<<dim3(1), dim3(128), 0, stream>>>(bqv, bkv, bvv, bsk, bias512);
  cvt_x<<<dim3((N * 128 / 8 + 255) / 256), blk256, 0, stream>>>(x, xb, N * 128);

  // CSR build
  hipMemsetAsync(deg, 0, (size_t)N * sizeof(int), stream);
  count_deg<<<dim3((E + 255) / 256), blk256, 0, stream>>>(dstI, deg, E);
  scan_pass1<<<dim3(SB), blk256, 0, stream>>>(deg, bsum, N);
  scan_pass2<<<dim3(1), dim3(1024), 0, stream>>>(bsum, SB);
  scan_pass3<<<dim3(SB), blk256, 0, stream>>>(deg, bsum, row_start, cursor, N, E);
  fill_edges<<<dim3((E + 255) / 256), blk256, 0, stream>>>(dstI, srcI, cursor, edge_src, E);

  // fused tconv projections: all 512 cols -> qkvb bf16 (q|k|v|xr)
  gemm_direct<128><<<dim3(GXM, 4), blk256, 0, stream>>>(xb, cWq, bias512,
                                                        qkvb, 512, 512, nullptr, 0,
                                                        N, 512, 0);

  // edge attention + gate + LN  -> x1 (fp32) + x1b (bf16)
  tconv_attn<<<dim3((N * H + 255) / 256), blk256, 0, stream>>>(qkvb, row_start, edge_src, wa, N);
  gate_ln<<<dim3((N + 3) / 4), blk256, 0, stream>>>(x, wa, qkvb, Wbeta, x1, x1b, N);

  // global MHA: fused K|V projection (N x 256, bf16 out; aliases qkvb which is now dead)
  gemm_direct<128><<<dim3(GXM, 2), blk256, 0, stream>>>(x1b, cNgK, ngb + 128,
                                                        kv16, 256, 256, nullptr, 0,
                                                        N, 256, 0);
  gemm_small<<<dim3(64), dim3(128), 0, stream>>>(gh, ngw, ngb, Qg, 64);
  glob_part<<<dim3(512, NCH), dim3(64), 0, stream>>>(Qg, kv16, Plog, pm, ps, pacc, MAXN);
  glob_merge<<<dim3(512), dim3(64), 0, stream>>>(pm, ps, pacc, Og, m_gl, is_gl);
  pker2<<<dim3((MAXN + 255) / 256, 8), blk256, 0, stream>>>(Plog, m_gl, is_gl, Pbuf, MAXN);
  regk<<<dim3(8), blk256, 0, stream>>>(Pbuf, offb, MAXN);
  regfin<<<dim3(1), dim3(64), 0, stream>>>(offb, outreg);

  gemm_small<<<dim3(64), dim3(128), 0, stream>>>(Og, ngow, ngob, gout, 64);
  ln_add<<<dim3(16), blk256, 0, stream>>>(gh, gout, outgh, nullptr, 64);   // new global_h

  // nodes attend to global tokens: fused Qn-proj -> attention -> out-proj (64-row tiles)
  gemm_small2<<<dim3(128), dim3(128), 0, stream>>>(outgh,
                                                   gnw + 128 * 128, gnb + 128, Kg,
                                                   gnw + 256 * 128, gnb + 256, Vg);
  gemm_node<<<dim3((N + 63) / 64), blk256, 0, stream>>>(x1b, cGnQ, gnb, Kg, Vg, cGnO, gnob,
                                                        wa, N, MAXN);
  ln_add<<<dim3((N + 3) / 4), blk256, 0, stream>>>(x1, wa, x1, x1b, N);   // x2 fp32 + bf16

  // fused FF + final LN -> d_out x
  gemm_ff<<<dim3(GXM), blk256, 0, stream>>>(x1b, cW1, b1v, cW2, b2v, ff2o, N);
  ln_add<<<dim3((N + 3) / 4), blk256, 0, stream>>>(x1, ff2o, outx, nullptr, N);
}